// Round 9
// baseline (244.044 us; speedup 1.0000x reference)
//
#include <hip/hip_runtime.h>

typedef short short8 __attribute__((ext_vector_type(8)));
typedef float f32x4 __attribute__((ext_vector_type(4)));

#define QSCALE 0.18033688011112042f  // 0.125 * log2(e), folded into Wq/bq

__device__ __forceinline__ unsigned short f2bf(float f) {
  unsigned u = __builtin_bit_cast(unsigned, f);
  u += 0x7fffu + ((u >> 16) & 1u);
  return (unsigned short)(u >> 16);
}

__device__ __forceinline__ void gload16(const void* g, void* l) {
  typedef __attribute__((address_space(1))) unsigned int gas;
  typedef __attribute__((address_space(3))) unsigned int las;
  __builtin_amdgcn_global_load_lds((gas*)(unsigned long long)g,
                                   (las*)(unsigned)(unsigned long long)l, 16, 0, 0);
}

#define MFMA16(a, b, c) __builtin_amdgcn_mfma_f32_16x16x32_bf16(a, b, c, 0, 0, 0)

// ---------------------------------------------------------------- weights ----
// W fp32 [k][n] -> Wt bf16 [n][k]; Wq additionally pre-scaled by QSCALE.
__global__ __launch_bounds__(256) void wtrans_kernel(
    const float* __restrict__ Wq, const float* __restrict__ Wk,
    const float* __restrict__ Wv, const float* __restrict__ Wo,
    unsigned short* __restrict__ Wt) {
  const int wsel = blockIdx.z;
  const float* W = wsel == 0 ? Wq : wsel == 1 ? Wk : wsel == 2 ? Wv : Wo;
  const float wscale = (wsel == 0) ? QSCALE : 1.0f;
  unsigned short* out = Wt + (long)wsel * 1048576;
  __shared__ float lds[64][65];
  const int t = threadIdx.x;
  const int k0 = blockIdx.x * 64, n0 = blockIdx.y * 64;
#pragma unroll
  for (int i = 0; i < 4; ++i) {
    int r = (t >> 4) + i * 16, c4 = (t & 15) * 4;
    float4 vv = *(const float4*)(W + (long)(k0 + r) * 1024 + n0 + c4);
    lds[r][c4] = vv.x; lds[r][c4 + 1] = vv.y; lds[r][c4 + 2] = vv.z; lds[r][c4 + 3] = vv.w;
  }
  __syncthreads();
#pragma unroll
  for (int i = 0; i < 16; ++i) {
    int flat = t + i * 256;
    int n = flat >> 6, kk = flat & 63;
    out[(long)(n0 + n) * 1024 + k0 + kk] = f2bf(lds[kk][n] * wscale);
  }
}

// ---------------------------------------------------------------- mask pack --
__global__ __launch_bounds__(256) void maskpack_kernel(const int* __restrict__ mask,
                                                       unsigned* __restrict__ bits) {
  const long n = 8388608;  // 2*2048*2048
  const long stride = (long)gridDim.x * 256;
  const int lane = threadIdx.x & 63;
  for (long i = (long)blockIdx.x * 256 + threadIdx.x; i < n; i += stride) {
    unsigned long long bal = __ballot(mask[i] != 0);
    if ((lane & 31) == 0) bits[i >> 5] = (unsigned)(bal >> (lane & 32));
  }
}

// ---------------------------------------------------------------- layernorm --
__global__ __launch_bounds__(256) void ln_kernel(
    const float* __restrict__ q, const float* __restrict__ k, const float* __restrict__ v,
    const float* __restrict__ gamma, const float* __restrict__ beta,
    unsigned short* __restrict__ lnq, unsigned short* __restrict__ lnk,
    unsigned short* __restrict__ lnv) {
  const int row = blockIdx.x, which = blockIdx.y;
  const float* x = (which == 0 ? q : which == 1 ? k : v) + (long)row * 1024;
  unsigned short* y = (which == 0 ? lnq : which == 1 ? lnk : lnv) + (long)row * 1024;
  const int t = threadIdx.x, lane = t & 63, wv = t >> 6;
  float4 xv = ((const float4*)x)[t];
  float s = xv.x + xv.y + xv.z + xv.w;
  float s2 = xv.x * xv.x + xv.y * xv.y + xv.z * xv.z + xv.w * xv.w;
#pragma unroll
  for (int off = 32; off > 0; off >>= 1) {
    s += __shfl_down(s, off);
    s2 += __shfl_down(s2, off);
  }
  __shared__ float red[8];
  if (lane == 0) { red[wv] = s; red[wv + 4] = s2; }
  __syncthreads();
  float tot = red[0] + red[1] + red[2] + red[3];
  float tot2 = red[4] + red[5] + red[6] + red[7];
  float mu = tot * (1.0f / 1024.0f);
  float var = tot2 * (1.0f / 1024.0f) - mu * mu;
  float rs = rsqrtf(var + 1e-5f);
  float4 g = ((const float4*)gamma)[t];
  float4 be = ((const float4*)beta)[t];
  ushort4 o;
  o.x = f2bf((xv.x - mu) * rs * g.x + be.x);
  o.y = f2bf((xv.y - mu) * rs * g.y + be.y);
  o.z = f2bf((xv.z - mu) * rs * g.z + be.z);
  o.w = f2bf((xv.w - mu) * rs * g.w + be.w);
  ((ushort4*)y)[t] = o;
}

// ---------------------------------------------------------------- GEMM -------
// MODE 0: bf16 out, heads layout [B,H,S,64]; z==2 writes V^T [BH][64][S] to outV.
// MODE 1: fp32 out row-major.
template <int BM, int MODE>
__global__ __launch_bounds__(256) void gemm_kernel(
    const unsigned short* __restrict__ A0, const unsigned short* __restrict__ A1,
    const unsigned short* __restrict__ A2, const unsigned short* __restrict__ Wt,
    const float* __restrict__ b0, const float* __restrict__ b1,
    const float* __restrict__ b2, unsigned short* __restrict__ outB,
    unsigned short* __restrict__ outV, float* __restrict__ outF) {
  constexpr int BK = 64;
  constexpr int MI = BM / 32;
  const int z = blockIdx.z;
  const unsigned short* A = z == 0 ? A0 : z == 1 ? A1 : A2;
  const unsigned short* Bt = Wt + (long)z * 1048576;
  const float* bias = z == 0 ? b0 : z == 1 ? b1 : b2;
  unsigned short* outz = outB + (long)z * 4194304;
  const float bscale = (MODE == 0 && z == 0) ? QSCALE : 1.0f;

  __shared__ char lds[BM * 128 + 16384];
  char* As = lds;
  char* Bs = lds + BM * 128;
  const int tid = threadIdx.x, lane = tid & 63, w = tid >> 6;
  const int wr = w >> 1, wc = w & 1;
  const int m0 = blockIdx.x * BM, n0 = blockIdx.y * 128;
  constexpr int K = 1024;
  constexpr int ACH = BM * 8 / 256;

  f32x4 acc[MI][4] = {};
  for (int kt = 0; kt < K / BK; ++kt) {
    __syncthreads();
#pragma unroll
    for (int i = 0; i < ACH; ++i) {
      int c = tid + i * 256;
      int row = c >> 3, pg = (c & 7) ^ (row & 7);
      gload16(A + (long)(m0 + row) * K + kt * BK + pg * 8, As + c * 16);
    }
#pragma unroll
    for (int i = 0; i < 4; ++i) {
      int c = tid + i * 256;
      int row = c >> 3, pg = (c & 7) ^ (row & 7);
      gload16(Bt + (long)(n0 + row) * K + kt * BK + pg * 8, Bs + c * 16);
    }
    asm volatile("s_waitcnt vmcnt(0)" ::: "memory");
    __syncthreads();
#pragma unroll
    for (int ks = 0; ks < 2; ++ks) {
      short8 af[MI], bf[4];
#pragma unroll
      for (int mi = 0; mi < MI; ++mi) {
        int row = wr * (BM / 2) + mi * 16 + (lane & 15);
        int part = (ks * 4 + (lane >> 4)) ^ (row & 7);
        af[mi] = *(const short8*)(As + row * 128 + part * 16);
      }
#pragma unroll
      for (int ni = 0; ni < 4; ++ni) {
        int row = wc * 64 + ni * 16 + (lane & 15);
        int part = (ks * 4 + (lane >> 4)) ^ (row & 7);
        bf[ni] = *(const short8*)(Bs + row * 128 + part * 16);
      }
#pragma unroll
      for (int mi = 0; mi < MI; ++mi)
#pragma unroll
        for (int ni = 0; ni < 4; ++ni)
          acc[mi][ni] = MFMA16(af[mi], bf[ni], acc[mi][ni]);
    }
  }
#pragma unroll
  for (int mi = 0; mi < MI; ++mi) {
    int mbase = m0 + wr * (BM / 2) + mi * 16 + ((lane >> 4) << 2);
#pragma unroll
    for (int ni = 0; ni < 4; ++ni) {
      int j = n0 + wc * 64 + ni * 16 + (lane & 15);
      float bj = bias[j] * bscale;
      float t0 = acc[mi][ni][0] + bj;
      float t1 = acc[mi][ni][1] + bj;
      float t2 = acc[mi][ni][2] + bj;
      float t3 = acc[mi][ni][3] + bj;
      if constexpr (MODE == 0) {
        int b = mbase >> 11, s = mbase & 2047;
        int h = j >> 6, d = j & 63;
        if (z == 2) {
          unsigned lo, hi;
          asm("v_cvt_pk_bf16_f32 %0, %1, %2" : "=v"(lo) : "v"(t0), "v"(t1));
          asm("v_cvt_pk_bf16_f32 %0, %1, %2" : "=v"(hi) : "v"(t2), "v"(t3));
          uint2 o; o.x = lo; o.y = hi;
          *(uint2*)(outV + ((long)(b * 16 + h) * 64 + d) * 2048 + s) = o;
        } else {
          long base = (((long)(b * 16 + h)) * 2048 + s) * 64 + d;
          outz[base] = f2bf(t0);
          outz[base + 64] = f2bf(t1);
          outz[base + 128] = f2bf(t2);
          outz[base + 192] = f2bf(t3);
        }
      } else {
        outF[(long)mbase * 1024 + j] = t0;
        outF[(long)(mbase + 1) * 1024 + j] = t1;
        outF[(long)(mbase + 2) * 1024 + j] = t2;
        outF[(long)(mbase + 3) * 1024 + j] = t3;
      }
    }
  }
}

// ---------------------------------------------------------------- attention --
// R3 structure (16 q/wave, 4-wave blocks, 16 waves/CU) with K read directly
// from global (L2-resident; fragment loads, no LDS round-trip). K(kt+1) is
// issued after QK^T(kt) reuses the same registers (no double-set -> no spill).
// V stays in LDS dbuf via global_load_lds; P per-wave in LDS.
__global__ __launch_bounds__(256, 4) void attn_kernel(
    const unsigned short* __restrict__ qh, const unsigned short* __restrict__ kh,
    const unsigned short* __restrict__ vt, const unsigned* __restrict__ mbits,
    unsigned short* __restrict__ O) {
  constexpr int S = 2048, NT = 32;
  __shared__ char lds[24576];  // V dbuf 2x8K | P 4x2K
  char* Vts = lds;
  const int tid = threadIdx.x, lane = tid & 63, w = tid >> 6;
  const int g = lane >> 4, c = lane & 15;
  char* Pw = lds + 16384 + w * 2048;  // [16 q][128B]

  // XCD-bijective swizzle: 1024 blocks -> 128 consecutive (4 heads) per XCD
  const int flat = blockIdx.y * 32 + blockIdx.x;
  const int fl2 = (flat & 7) * 128 + (flat >> 3);
  const int qb = fl2 & 31, bh = fl2 >> 5, b = bh >> 4;

  const unsigned short* qp = qh + (long)bh * S * 64;
  const unsigned short* kp = kh + (long)bh * S * 64;
  const unsigned short* vp = vt + (long)bh * 64 * S;
  unsigned short* op = O + (long)bh * S * 64;
  const unsigned* mrow = mbits + (long)b * S * 64;
  const int q0 = qb * 64 + w * 16;
  const int myq = q0 + c;

  // Q as B-frags (pre-scaled by QSCALE upstream)
  short8 bq_[2];
#pragma unroll
  for (int ds = 0; ds < 2; ++ds)
    bq_[ds] = *(const short8*)(qp + (long)myq * 64 + ds * 32 + g * 8);

  f32x4 o_acc[4] = {};
  float lpart = 0.f;

#define STAGEV(KT, BUF)                                                             \
  {                                                                                 \
    _Pragma("unroll") for (int i = 0; i < 2; ++i) {                                 \
      int cc = tid + i * 256;                                                       \
      int row = cc >> 3, pg = (cc & 7) ^ (row & 7);                                 \
      gload16(vp + (long)row * S + (KT)*64 + pg * 8, Vts + (BUF)*8192 + cc * 16);   \
    }                                                                               \
  }

  // A-frag of swapped QK^T: kA[ds*4+kf] lane(g,c) = K[kt*64+kf*16+c][ds*32+g*8 ..+7]
#define LOADK(KT)                                                                   \
  {                                                                                 \
    _Pragma("unroll") for (int i = 0; i < 8; ++i) {                                 \
      kA[i] = *(const short8*)(kp + (((long)(KT)*64 + (i & 3) * 16 + c) << 6) +     \
                               (i >> 2) * 32 + g * 8);                              \
    }                                                                               \
  }

  short8 kA[8];
  STAGEV(0, 0);
  uint2 mcur = *(const uint2*)(mrow + (long)myq * 64);
  uint2 mnxt = mcur;
  LOADK(0);

  for (int kt = 0; kt < NT; ++kt) {
    const int cur = kt & 1;
    if (kt + 1 < NT) {
      STAGEV(kt + 1, cur ^ 1);
      mnxt = *(const uint2*)(mrow + (long)myq * 64 + (kt + 1) * 2);
      // outstanding: [V(kt)2, m(kt)1, K(kt)8] + [V(kt+1)2, m(kt+1)1] = 14.
      // vmcnt(3) drains the current tile's 11, keeps next-tile V+mask in flight.
      asm volatile("s_waitcnt vmcnt(3)" ::: "memory");
    } else {
      asm volatile("s_waitcnt vmcnt(0)" ::: "memory");
    }
    __builtin_amdgcn_s_barrier();

    // QK^T (swapped): A = K-frags from registers, B = Q
    f32x4 sc[4] = {};
    __builtin_amdgcn_s_setprio(1);
#pragma unroll
    for (int ds = 0; ds < 2; ++ds)
#pragma unroll
      for (int kf = 0; kf < 4; ++kf)
        sc[kf] = MFMA16(kA[ds * 4 + kf], bq_[ds], sc[kf]);
    __builtin_amdgcn_s_setprio(0);

    // prefetch next tile's K into the same registers (WAR-safe after use)
    if (kt + 1 < NT) LOADK(kt + 1);

    // softmax (fixed-max, pre-scaled): p = live ? 2^s : 0
    unsigned ws0 = mcur.x >> (g * 4), ws1 = mcur.y >> (g * 4);
#pragma unroll
    for (int kf = 0; kf < 4; ++kf) {
      unsigned wsh = ((kf >= 2) ? ws1 : ws0) >> ((kf & 1) * 16);
      float pv0 = __builtin_amdgcn_exp2f(sc[kf][0]);
      float pv1 = __builtin_amdgcn_exp2f(sc[kf][1]);
      float pv2 = __builtin_amdgcn_exp2f(sc[kf][2]);
      float pv3 = __builtin_amdgcn_exp2f(sc[kf][3]);
      pv0 = (wsh & 1u) ? pv0 : 0.f;
      pv1 = (wsh & 2u) ? pv1 : 0.f;
      pv2 = (wsh & 4u) ? pv2 : 0.f;
      pv3 = (wsh & 8u) ? pv3 : 0.f;
      lpart += (pv0 + pv1) + (pv2 + pv3);
      unsigned plo, phi;
      asm("v_cvt_pk_bf16_f32 %0, %1, %2" : "=v"(plo) : "v"(pv0), "v"(pv1));
      asm("v_cvt_pk_bf16_f32 %0, %1, %2" : "=v"(phi) : "v"(pv2), "v"(pv3));
      uint2 pk2; pk2.x = plo; pk2.y = phi;
      int plog = kf * 2 + (g >> 1);
      *(uint2*)(Pw + c * 128 + ((plog ^ (c & 7)) * 16) + (g & 1) * 8) = pk2;
    }
    mcur = mnxt;

    // PV (V from LDS)
    const char* Vb = Vts + cur * 8192;
    __builtin_amdgcn_s_setprio(1);
#pragma unroll
    for (int ks = 0; ks < 2; ++ks) {
      int part = ks * 4 + g;
      short8 pa = *(const short8*)(Pw + c * 128 + ((part ^ (c & 7)) * 16));
#pragma unroll
      for (int nd = 0; nd < 4; ++nd) {
        int d = nd * 16 + c;
        short8 bv = *(const short8*)(Vb + d * 128 + ((part ^ (d & 7)) * 16));
        o_acc[nd] = MFMA16(pa, bv, o_acc[nd]);
      }
    }
    __builtin_amdgcn_s_setprio(0);

    // drain LDS reads before barrier so next stage can't overwrite in-flight
    asm volatile("s_waitcnt lgkmcnt(0)" ::: "memory");
    __builtin_amdgcn_s_barrier();
  }
#undef LOADK
#undef STAGEV

  // epilogue: reduce l across the 4 g-groups, divide, store
  lpart += __shfl_xor(lpart, 16);
  lpart += __shfl_xor(lpart, 32);
#pragma unroll
  for (int r = 0; r < 4; ++r) {
    float lr = __shfl(lpart, g * 4 + r);
    float inv = 1.0f / lr;
    int qrow = q0 + g * 4 + r;
#pragma unroll
    for (int nd = 0; nd < 4; ++nd)
      op[(long)qrow * 64 + nd * 16 + c] = f2bf(o_acc[nd][r] * inv);
  }
}

// ---------------------------------------------------------------- launch -----
extern "C" void kernel_launch(void* const* d_in, const int* in_sizes, int n_in,
                              void* d_out, int out_size, void* d_ws, size_t ws_size,
                              hipStream_t stream) {
  const float* q = (const float*)d_in[0];
  const float* k = (const float*)d_in[1];
  const float* v = (const float*)d_in[2];
  const int* mask = (const int*)d_in[3];
  const float* Wq = (const float*)d_in[4];
  const float* bq = (const float*)d_in[5];
  const float* Wk = (const float*)d_in[6];
  const float* bk = (const float*)d_in[7];
  const float* Wv = (const float*)d_in[8];
  const float* bv = (const float*)d_in[9];
  const float* Wo = (const float*)d_in[10];
  const float* bo = (const float*)d_in[11];
  const float* gamma = (const float*)d_in[12];
  const float* beta = (const float*)d_in[13];
  float* out = (float*)d_out;

  char* ws = (char*)d_ws;
  unsigned short* Wt = (unsigned short*)ws;                         // 8 MB
  unsigned* mbits = (unsigned*)(ws + 8u * 1024 * 1024);             // 1 MB
  unsigned short* lnq = (unsigned short*)(ws + 9u * 1024 * 1024);   // 8 MB
  unsigned short* lnk = lnq + 4194304;
  unsigned short* lnv = lnk + 4194304;
  unsigned short* qh = lnv + 4194304;
  unsigned short* kh = qh + 4194304;
  unsigned short* vtb = kh + 4194304;  // V^T written directly by QKV GEMM (z==2)
  unsigned short* Ob = lnq;            // alias: lnq dead after QKV GEMM

  wtrans_kernel<<<dim3(16, 16, 4), 256, 0, stream>>>(Wq, Wk, Wv, Wo, Wt);
  maskpack_kernel<<<1024, 256, 0, stream>>>(mask, mbits);
  ln_kernel<<<dim3(4096, 3), 256, 0, stream>>>(q, k, v, gamma, beta, lnq, lnk, lnv);
  gemm_kernel<128, 0><<<dim3(32, 8, 3), 256, 0, stream>>>(lnq, lnk, lnv, Wt, bq, bk, bv,
                                                          qh, vtb, nullptr);
  attn_kernel<<<dim3(32, 32), 256, 0, stream>>>(qh, kh, vtb, mbits, Ob);
  gemm_kernel<128, 1><<<dim3(32, 8, 1), 256, 0, stream>>>(Ob, Ob, Ob, Wt + 3 * 1048576,
                                                          bo, bo, bo, nullptr, nullptr, out);
}

// Round 10
// 151.686 us; speedup vs baseline: 1.6089x; 1.6089x over previous
//
#include <hip/hip_runtime.h>

typedef short short8 __attribute__((ext_vector_type(8)));
typedef float f32x4 __attribute__((ext_vector_type(4)));

#define QSCALE 0.18033688011112042f  // 0.125 * log2(e), folded into Wq/bq

__device__ __forceinline__ unsigned short f2bf(float f) {
  unsigned u = __builtin_bit_cast(unsigned, f);
  u += 0x7fffu + ((u >> 16) & 1u);
  return (unsigned short)(u >> 16);
}

__device__ __forceinline__ void gload16(const void* g, void* l) {
  typedef __attribute__((address_space(1))) unsigned int gas;
  typedef __attribute__((address_space(3))) unsigned int las;
  __builtin_amdgcn_global_load_lds((gas*)(unsigned long long)g,
                                   (las*)(unsigned)(unsigned long long)l, 16, 0, 0);
}

#define MFMA16(a, b, c) __builtin_amdgcn_mfma_f32_16x16x32_bf16(a, b, c, 0, 0, 0)

// ---------------------------------------------------------------- weights ----
// W fp32 [k][n] -> Wt bf16 [n][k]; Wq additionally pre-scaled by QSCALE.
__global__ __launch_bounds__(256) void wtrans_kernel(
    const float* __restrict__ Wq, const float* __restrict__ Wk,
    const float* __restrict__ Wv, const float* __restrict__ Wo,
    unsigned short* __restrict__ Wt) {
  const int wsel = blockIdx.z;
  const float* W = wsel == 0 ? Wq : wsel == 1 ? Wk : wsel == 2 ? Wv : Wo;
  const float wscale = (wsel == 0) ? QSCALE : 1.0f;
  unsigned short* out = Wt + (long)wsel * 1048576;
  __shared__ float lds[64][65];
  const int t = threadIdx.x;
  const int k0 = blockIdx.x * 64, n0 = blockIdx.y * 64;
#pragma unroll
  for (int i = 0; i < 4; ++i) {
    int r = (t >> 4) + i * 16, c4 = (t & 15) * 4;
    float4 vv = *(const float4*)(W + (long)(k0 + r) * 1024 + n0 + c4);
    lds[r][c4] = vv.x; lds[r][c4 + 1] = vv.y; lds[r][c4 + 2] = vv.z; lds[r][c4 + 3] = vv.w;
  }
  __syncthreads();
#pragma unroll
  for (int i = 0; i < 16; ++i) {
    int flat = t + i * 256;
    int n = flat >> 6, kk = flat & 63;
    out[(long)(n0 + n) * 1024 + k0 + kk] = f2bf(lds[kk][n] * wscale);
  }
}

// ---------------------------------------------------------------- mask pack --
__global__ __launch_bounds__(256) void maskpack_kernel(const int* __restrict__ mask,
                                                       unsigned* __restrict__ bits) {
  const long n = 8388608;  // 2*2048*2048
  const long stride = (long)gridDim.x * 256;
  const int lane = threadIdx.x & 63;
  for (long i = (long)blockIdx.x * 256 + threadIdx.x; i < n; i += stride) {
    unsigned long long bal = __ballot(mask[i] != 0);
    if ((lane & 31) == 0) bits[i >> 5] = (unsigned)(bal >> (lane & 32));
  }
}

// ---------------------------------------------------------------- layernorm --
__global__ __launch_bounds__(256) void ln_kernel(
    const float* __restrict__ q, const float* __restrict__ k, const float* __restrict__ v,
    const float* __restrict__ gamma, const float* __restrict__ beta,
    unsigned short* __restrict__ lnq, unsigned short* __restrict__ lnk,
    unsigned short* __restrict__ lnv) {
  const int row = blockIdx.x, which = blockIdx.y;
  const float* x = (which == 0 ? q : which == 1 ? k : v) + (long)row * 1024;
  unsigned short* y = (which == 0 ? lnq : which == 1 ? lnk : lnv) + (long)row * 1024;
  const int t = threadIdx.x, lane = t & 63, wv = t >> 6;
  float4 xv = ((const float4*)x)[t];
  float s = xv.x + xv.y + xv.z + xv.w;
  float s2 = xv.x * xv.x + xv.y * xv.y + xv.z * xv.z + xv.w * xv.w;
#pragma unroll
  for (int off = 32; off > 0; off >>= 1) {
    s += __shfl_down(s, off);
    s2 += __shfl_down(s2, off);
  }
  __shared__ float red[8];
  if (lane == 0) { red[wv] = s; red[wv + 4] = s2; }
  __syncthreads();
  float tot = red[0] + red[1] + red[2] + red[3];
  float tot2 = red[4] + red[5] + red[6] + red[7];
  float mu = tot * (1.0f / 1024.0f);
  float var = tot2 * (1.0f / 1024.0f) - mu * mu;
  float rs = rsqrtf(var + 1e-5f);
  float4 g = ((const float4*)gamma)[t];
  float4 be = ((const float4*)beta)[t];
  ushort4 o;
  o.x = f2bf((xv.x - mu) * rs * g.x + be.x);
  o.y = f2bf((xv.y - mu) * rs * g.y + be.y);
  o.z = f2bf((xv.z - mu) * rs * g.z + be.z);
  o.w = f2bf((xv.w - mu) * rs * g.w + be.w);
  ((ushort4*)y)[t] = o;
}

// ---------------------------------------------------------------- GEMM -------
// MODE 0: bf16 out, heads layout [B,H,S,64]; z==2 writes V^T [BH][64][S] to outV.
// MODE 1: fp32 out row-major.
template <int BM, int MODE>
__global__ __launch_bounds__(256) void gemm_kernel(
    const unsigned short* __restrict__ A0, const unsigned short* __restrict__ A1,
    const unsigned short* __restrict__ A2, const unsigned short* __restrict__ Wt,
    const float* __restrict__ b0, const float* __restrict__ b1,
    const float* __restrict__ b2, unsigned short* __restrict__ outB,
    unsigned short* __restrict__ outV, float* __restrict__ outF) {
  constexpr int BK = 64;
  constexpr int MI = BM / 32;
  const int z = blockIdx.z;
  const unsigned short* A = z == 0 ? A0 : z == 1 ? A1 : A2;
  const unsigned short* Bt = Wt + (long)z * 1048576;
  const float* bias = z == 0 ? b0 : z == 1 ? b1 : b2;
  unsigned short* outz = outB + (long)z * 4194304;
  const float bscale = (MODE == 0 && z == 0) ? QSCALE : 1.0f;

  __shared__ char lds[BM * 128 + 16384];
  char* As = lds;
  char* Bs = lds + BM * 128;
  const int tid = threadIdx.x, lane = tid & 63, w = tid >> 6;
  const int wr = w >> 1, wc = w & 1;
  const int m0 = blockIdx.x * BM, n0 = blockIdx.y * 128;
  constexpr int K = 1024;
  constexpr int ACH = BM * 8 / 256;

  f32x4 acc[MI][4] = {};
  for (int kt = 0; kt < K / BK; ++kt) {
    __syncthreads();
#pragma unroll
    for (int i = 0; i < ACH; ++i) {
      int c = tid + i * 256;
      int row = c >> 3, pg = (c & 7) ^ (row & 7);
      gload16(A + (long)(m0 + row) * K + kt * BK + pg * 8, As + c * 16);
    }
#pragma unroll
    for (int i = 0; i < 4; ++i) {
      int c = tid + i * 256;
      int row = c >> 3, pg = (c & 7) ^ (row & 7);
      gload16(Bt + (long)(n0 + row) * K + kt * BK + pg * 8, Bs + c * 16);
    }
    asm volatile("s_waitcnt vmcnt(0)" ::: "memory");
    __syncthreads();
#pragma unroll
    for (int ks = 0; ks < 2; ++ks) {
      short8 af[MI], bf[4];
#pragma unroll
      for (int mi = 0; mi < MI; ++mi) {
        int row = wr * (BM / 2) + mi * 16 + (lane & 15);
        int part = (ks * 4 + (lane >> 4)) ^ (row & 7);
        af[mi] = *(const short8*)(As + row * 128 + part * 16);
      }
#pragma unroll
      for (int ni = 0; ni < 4; ++ni) {
        int row = wc * 64 + ni * 16 + (lane & 15);
        int part = (ks * 4 + (lane >> 4)) ^ (row & 7);
        bf[ni] = *(const short8*)(Bs + row * 128 + part * 16);
      }
#pragma unroll
      for (int mi = 0; mi < MI; ++mi)
#pragma unroll
        for (int ni = 0; ni < 4; ++ni)
          acc[mi][ni] = MFMA16(af[mi], bf[ni], acc[mi][ni]);
    }
  }
#pragma unroll
  for (int mi = 0; mi < MI; ++mi) {
    int mbase = m0 + wr * (BM / 2) + mi * 16 + ((lane >> 4) << 2);
#pragma unroll
    for (int ni = 0; ni < 4; ++ni) {
      int j = n0 + wc * 64 + ni * 16 + (lane & 15);
      float bj = bias[j] * bscale;
      float t0 = acc[mi][ni][0] + bj;
      float t1 = acc[mi][ni][1] + bj;
      float t2 = acc[mi][ni][2] + bj;
      float t3 = acc[mi][ni][3] + bj;
      if constexpr (MODE == 0) {
        int b = mbase >> 11, s = mbase & 2047;
        int h = j >> 6, d = j & 63;
        if (z == 2) {
          unsigned lo, hi;
          asm("v_cvt_pk_bf16_f32 %0, %1, %2" : "=v"(lo) : "v"(t0), "v"(t1));
          asm("v_cvt_pk_bf16_f32 %0, %1, %2" : "=v"(hi) : "v"(t2), "v"(t3));
          uint2 o; o.x = lo; o.y = hi;
          *(uint2*)(outV + ((long)(b * 16 + h) * 64 + d) * 2048 + s) = o;
        } else {
          long base = (((long)(b * 16 + h)) * 2048 + s) * 64 + d;
          outz[base] = f2bf(t0);
          outz[base + 64] = f2bf(t1);
          outz[base + 128] = f2bf(t2);
          outz[base + 192] = f2bf(t3);
        }
      } else {
        outF[(long)mbase * 1024 + j] = t0;
        outF[(long)(mbase + 1) * 1024 + j] = t1;
        outF[(long)(mbase + 2) * 1024 + j] = t2;
        outF[(long)(mbase + 3) * 1024 + j] = t3;
      }
    }
  }
}

// ---------------------------------------------------------------- attention --
// R3 structure (67.5 us proven): swapped-QK^T, fixed-max softmax, K+V LDS dbuf,
// 16 q/wave, 4-wave blocks, 16 waves/CU. NEW: phase-staggered tile order —
// each co-resident block starts at a different KV tile (kt0 = (fl2&3)*8) so
// the 4 blocks/CU keep their exp2/LDS/MFMA phases decorrelated. Valid because
// fixed-max softmax is tile-order independent.
__global__ __launch_bounds__(256, 4) void attn_kernel(
    const unsigned short* __restrict__ qh, const unsigned short* __restrict__ kh,
    const unsigned short* __restrict__ vt, const unsigned* __restrict__ mbits,
    unsigned short* __restrict__ O) {
  constexpr int S = 2048, NT = 32;
  __shared__ char lds[40960];  // K dbuf 16K | V dbuf 16K | P 4x2K
  char* Ks = lds;
  char* Vts = lds + 16384;
  const int tid = threadIdx.x, lane = tid & 63, w = tid >> 6;
  const int g = lane >> 4, c = lane & 15;
  char* Pw = lds + 32768 + w * 2048;  // [16 q][128B]

  // XCD-bijective swizzle: 1024 blocks -> 128 consecutive (4 heads) per XCD
  const int flat = blockIdx.y * 32 + blockIdx.x;
  const int fl2 = (flat & 7) * 128 + (flat >> 3);
  const int qb = fl2 & 31, bh = fl2 >> 5, b = bh >> 4;
  const int kt0 = (fl2 & 3) * 8;  // phase stagger across co-resident blocks

  const unsigned short* qp = qh + (long)bh * S * 64;
  const unsigned short* kp = kh + (long)bh * S * 64;
  const unsigned short* vp = vt + (long)bh * 64 * S;
  unsigned short* op = O + (long)bh * S * 64;
  const unsigned* mrow = mbits + (long)b * S * 64;
  const int q0 = qb * 64 + w * 16;
  const int myq = q0 + c;

  // Q as B-frags (pre-scaled by QSCALE upstream)
  short8 bq_[2];
#pragma unroll
  for (int ds = 0; ds < 2; ++ds)
    bq_[ds] = *(const short8*)(qp + (long)myq * 64 + ds * 32 + g * 8);

  f32x4 o_acc[4] = {};
  float lpart = 0.f;

#define STAGE(KT, BUF)                                                              \
  {                                                                                 \
    _Pragma("unroll") for (int i = 0; i < 2; ++i) {                                 \
      int cc = tid + i * 256;                                                       \
      int row = cc >> 3, pg = (cc & 7) ^ (row & 7);                                 \
      gload16(kp + (long)((KT)*64 + row) * 64 + pg * 8, Ks + (BUF)*8192 + cc * 16); \
    }                                                                               \
    _Pragma("unroll") for (int i = 0; i < 2; ++i) {                                 \
      int cc = tid + i * 256;                                                       \
      int row = cc >> 3, pg = (cc & 7) ^ (row & 7);                                 \
      gload16(vp + (long)row * S + (KT)*64 + pg * 8, Vts + (BUF)*8192 + cc * 16);   \
    }                                                                               \
  }

  STAGE(kt0, 0);
  uint2 mcur = *(const uint2*)(mrow + (long)myq * 64 + kt0 * 2);
  uint2 mnxt = mcur;

  for (int kt = 0; kt < NT; ++kt) {
    const int cur = kt & 1;
    if (kt + 1 < NT) {
      const int nx = (kt0 + kt + 1) & 31;
      STAGE(nx, cur ^ 1);
      mnxt = *(const uint2*)(mrow + (long)myq * 64 + nx * 2);
      // 5 loads issued this iter (4 stage + 1 mask); drain exactly the
      // previous tile's 5 -> current K/V + mask ready, next-tile stays in flight.
      asm volatile("s_waitcnt vmcnt(5)" ::: "memory");
    } else {
      asm volatile("s_waitcnt vmcnt(0)" ::: "memory");
    }
    __builtin_amdgcn_s_barrier();

    // QK^T (swapped): sc[kf] rows = k-local, cols = q
    f32x4 sc[4] = {};
    const char* Kb = Ks + cur * 8192;
    __builtin_amdgcn_s_setprio(1);
#pragma unroll
    for (int ds = 0; ds < 2; ++ds) {
#pragma unroll
      for (int kf = 0; kf < 4; ++kf) {
        int row = kf * 16 + c;
        int part = (ds * 4 + g) ^ (row & 7);
        short8 ak = *(const short8*)(Kb + row * 128 + part * 16);
        sc[kf] = MFMA16(ak, bq_[ds], sc[kf]);
      }
    }
    __builtin_amdgcn_s_setprio(0);

    // softmax (fixed-max, pre-scaled): p = live ? 2^s : 0
    unsigned ws0 = mcur.x >> (g * 4), ws1 = mcur.y >> (g * 4);
#pragma unroll
    for (int kf = 0; kf < 4; ++kf) {
      unsigned wsh = ((kf >= 2) ? ws1 : ws0) >> ((kf & 1) * 16);
      float pv0 = __builtin_amdgcn_exp2f(sc[kf][0]);
      float pv1 = __builtin_amdgcn_exp2f(sc[kf][1]);
      float pv2 = __builtin_amdgcn_exp2f(sc[kf][2]);
      float pv3 = __builtin_amdgcn_exp2f(sc[kf][3]);
      pv0 = (wsh & 1u) ? pv0 : 0.f;
      pv1 = (wsh & 2u) ? pv1 : 0.f;
      pv2 = (wsh & 4u) ? pv2 : 0.f;
      pv3 = (wsh & 8u) ? pv3 : 0.f;
      lpart += (pv0 + pv1) + (pv2 + pv3);
      unsigned plo, phi;
      asm("v_cvt_pk_bf16_f32 %0, %1, %2" : "=v"(plo) : "v"(pv0), "v"(pv1));
      asm("v_cvt_pk_bf16_f32 %0, %1, %2" : "=v"(phi) : "v"(pv2), "v"(pv3));
      uint2 pk2; pk2.x = plo; pk2.y = phi;
      int plog = kf * 2 + (g >> 1);
      *(uint2*)(Pw + c * 128 + ((plog ^ (c & 7)) * 16) + (g & 1) * 8) = pk2;
    }
    mcur = mnxt;

    // PV
    const char* Vb = Vts + cur * 8192;
    __builtin_amdgcn_s_setprio(1);
#pragma unroll
    for (int ks = 0; ks < 2; ++ks) {
      int part = ks * 4 + g;
      short8 pa = *(const short8*)(Pw + c * 128 + ((part ^ (c & 7)) * 16));
#pragma unroll
      for (int nd = 0; nd < 4; ++nd) {
        int d = nd * 16 + c;
        short8 bv = *(const short8*)(Vb + d * 128 + ((part ^ (d & 7)) * 16));
        o_acc[nd] = MFMA16(pa, bv, o_acc[nd]);
      }
    }
    __builtin_amdgcn_s_setprio(0);

    // drain LDS reads before barrier so next stage can't overwrite in-flight
    asm volatile("s_waitcnt lgkmcnt(0)" ::: "memory");
    __builtin_amdgcn_sched_barrier(0);
    __builtin_amdgcn_s_barrier();
  }
#undef STAGE

  // epilogue: reduce l across the 4 g-groups, divide, store
  lpart += __shfl_xor(lpart, 16);
  lpart += __shfl_xor(lpart, 32);
#pragma unroll
  for (int r = 0; r < 4; ++r) {
    float lr = __shfl(lpart, g * 4 + r);
    float inv = 1.0f / lr;
    int qrow = q0 + g * 4 + r;
#pragma unroll
    for (int nd = 0; nd < 4; ++nd)
      op[(long)qrow * 64 + nd * 16 + c] = f2bf(o_acc[nd][r] * inv);
  }
}

// ---------------------------------------------------------------- launch -----
extern "C" void kernel_launch(void* const* d_in, const int* in_sizes, int n_in,
                              void* d_out, int out_size, void* d_ws, size_t ws_size,
                              hipStream_t stream) {
  const float* q = (const float*)d_in[0];
  const float* k = (const float*)d_in[1];
  const float* v = (const float*)d_in[2];
  const int* mask = (const int*)d_in[3];
  const float* Wq = (const float*)d_in[4];
  const float* bq = (const float*)d_in[5];
  const float* Wk = (const float*)d_in[6];
  const float* bk = (const float*)d_in[7];
  const float* Wv = (const float*)d_in[8];
  const float* bv = (const float*)d_in[9];
  const float* Wo = (const float*)d_in[10];
  const float* bo = (const float*)d_in[11];
  const float* gamma = (const float*)d_in[12];
  const float* beta = (const float*)d_in[13];
  float* out = (float*)d_out;

  char* ws = (char*)d_ws;
  unsigned short* Wt = (unsigned short*)ws;                         // 8 MB
  unsigned* mbits = (unsigned*)(ws + 8u * 1024 * 1024);             // 1 MB
  unsigned short* lnq = (unsigned short*)(ws + 9u * 1024 * 1024);   // 8 MB
  unsigned short* lnk = lnq + 4194304;
  unsigned short* lnv = lnk + 4194304;
  unsigned short* qh = lnv + 4194304;
  unsigned short* kh = qh + 4194304;
  unsigned short* vtb = kh + 4194304;  // V^T written directly by QKV GEMM (z==2)
  unsigned short* Ob = lnq;            // alias: lnq dead after QKV GEMM

  wtrans_kernel<<<dim3(16, 16, 4), 256, 0, stream>>>(Wq, Wk, Wv, Wo, Wt);
  maskpack_kernel<<<1024, 256, 0, stream>>>(mask, mbits);
  ln_kernel<<<dim3(4096, 3), 256, 0, stream>>>(q, k, v, gamma, beta, lnq, lnk, lnv);
  gemm_kernel<128, 0><<<dim3(32, 8, 3), 256, 0, stream>>>(lnq, lnk, lnv, Wt, bq, bk, bv,
                                                          qh, vtb, nullptr);
  attn_kernel<<<dim3(32, 32), 256, 0, stream>>>(qh, kh, vtb, mbits, Ob);
  gemm_kernel<64, 1><<<dim3(64, 8, 1), 256, 0, stream>>>(Ob, Ob, Ob, Wt + 3 * 1048576,
                                                         bo, bo, bo, nullptr, nullptr, out);
}

// Round 11
// 149.166 us; speedup vs baseline: 1.6361x; 1.0169x over previous
//
#include <hip/hip_runtime.h>

typedef short short8 __attribute__((ext_vector_type(8)));
typedef float f32x4 __attribute__((ext_vector_type(4)));

#define QSCALE 0.18033688011112042f  // 0.125 * log2(e), folded into Wq/bq

__device__ __forceinline__ unsigned short f2bf(float f) {
  unsigned u = __builtin_bit_cast(unsigned, f);
  u += 0x7fffu + ((u >> 16) & 1u);
  return (unsigned short)(u >> 16);
}

__device__ __forceinline__ void gload16(const void* g, void* l) {
  typedef __attribute__((address_space(1))) unsigned int gas;
  typedef __attribute__((address_space(3))) unsigned int las;
  __builtin_amdgcn_global_load_lds((gas*)(unsigned long long)g,
                                   (las*)(unsigned)(unsigned long long)l, 16, 0, 0);
}

__device__ __forceinline__ short8 mk8(unsigned r0, unsigned r1, unsigned r2, unsigned r3) {
  union { unsigned u[4]; short8 s; } t;
  t.u[0] = r0; t.u[1] = r1; t.u[2] = r2; t.u[3] = r3;
  return t.s;
}

#define MFMA16(a, b, c) __builtin_amdgcn_mfma_f32_16x16x32_bf16(a, b, c, 0, 0, 0)

// ---------------------------------------------------------------- weights ----
// W fp32 [k][n] -> Wt bf16 [n][k]; Wq additionally pre-scaled by QSCALE.
__global__ __launch_bounds__(256) void wtrans_kernel(
    const float* __restrict__ Wq, const float* __restrict__ Wk,
    const float* __restrict__ Wv, const float* __restrict__ Wo,
    unsigned short* __restrict__ Wt) {
  const int wsel = blockIdx.z;
  const float* W = wsel == 0 ? Wq : wsel == 1 ? Wk : wsel == 2 ? Wv : Wo;
  const float wscale = (wsel == 0) ? QSCALE : 1.0f;
  unsigned short* out = Wt + (long)wsel * 1048576;
  __shared__ float lds[64][65];
  const int t = threadIdx.x;
  const int k0 = blockIdx.x * 64, n0 = blockIdx.y * 64;
#pragma unroll
  for (int i = 0; i < 4; ++i) {
    int r = (t >> 4) + i * 16, c4 = (t & 15) * 4;
    float4 vv = *(const float4*)(W + (long)(k0 + r) * 1024 + n0 + c4);
    lds[r][c4] = vv.x; lds[r][c4 + 1] = vv.y; lds[r][c4 + 2] = vv.z; lds[r][c4 + 3] = vv.w;
  }
  __syncthreads();
#pragma unroll
  for (int i = 0; i < 16; ++i) {
    int flat = t + i * 256;
    int n = flat >> 6, kk = flat & 63;
    out[(long)(n0 + n) * 1024 + k0 + kk] = f2bf(lds[kk][n] * wscale);
  }
}

// ---------------------------------------------------------------- mask pack --
__global__ __launch_bounds__(256) void maskpack_kernel(const int* __restrict__ mask,
                                                       unsigned* __restrict__ bits) {
  const long n = 8388608;  // 2*2048*2048
  const long stride = (long)gridDim.x * 256;
  const int lane = threadIdx.x & 63;
  for (long i = (long)blockIdx.x * 256 + threadIdx.x; i < n; i += stride) {
    unsigned long long bal = __ballot(mask[i] != 0);
    if ((lane & 31) == 0) bits[i >> 5] = (unsigned)(bal >> (lane & 32));
  }
}

// ---------------------------------------------------------------- layernorm --
__global__ __launch_bounds__(256) void ln_kernel(
    const float* __restrict__ q, const float* __restrict__ k, const float* __restrict__ v,
    const float* __restrict__ gamma, const float* __restrict__ beta,
    unsigned short* __restrict__ lnq, unsigned short* __restrict__ lnk,
    unsigned short* __restrict__ lnv) {
  const int row = blockIdx.x, which = blockIdx.y;
  const float* x = (which == 0 ? q : which == 1 ? k : v) + (long)row * 1024;
  unsigned short* y = (which == 0 ? lnq : which == 1 ? lnk : lnv) + (long)row * 1024;
  const int t = threadIdx.x, lane = t & 63, wv = t >> 6;
  float4 xv = ((const float4*)x)[t];
  float s = xv.x + xv.y + xv.z + xv.w;
  float s2 = xv.x * xv.x + xv.y * xv.y + xv.z * xv.z + xv.w * xv.w;
#pragma unroll
  for (int off = 32; off > 0; off >>= 1) {
    s += __shfl_down(s, off);
    s2 += __shfl_down(s2, off);
  }
  __shared__ float red[8];
  if (lane == 0) { red[wv] = s; red[wv + 4] = s2; }
  __syncthreads();
  float tot = red[0] + red[1] + red[2] + red[3];
  float tot2 = red[4] + red[5] + red[6] + red[7];
  float mu = tot * (1.0f / 1024.0f);
  float var = tot2 * (1.0f / 1024.0f) - mu * mu;
  float rs = rsqrtf(var + 1e-5f);
  float4 g = ((const float4*)gamma)[t];
  float4 be = ((const float4*)beta)[t];
  ushort4 o;
  o.x = f2bf((xv.x - mu) * rs * g.x + be.x);
  o.y = f2bf((xv.y - mu) * rs * g.y + be.y);
  o.z = f2bf((xv.z - mu) * rs * g.z + be.z);
  o.w = f2bf((xv.w - mu) * rs * g.w + be.w);
  ((ushort4*)y)[t] = o;
}

// ---------------------------------------------------------------- GEMM -------
// MODE 0: bf16 out, heads layout [B,H,S,64]; z==2 writes V^T [BH][64][S] to outV
// with kv-slot permutation (pos = (s&~31)|((s>>2)&3)<<3|((s>>4)&1)<<2) so the
// attention's PV A-fragment is lane-local (P never touches LDS).
// MODE 1: fp32 out row-major.
template <int BM, int MODE>
__global__ __launch_bounds__(256) void gemm_kernel(
    const unsigned short* __restrict__ A0, const unsigned short* __restrict__ A1,
    const unsigned short* __restrict__ A2, const unsigned short* __restrict__ Wt,
    const float* __restrict__ b0, const float* __restrict__ b1,
    const float* __restrict__ b2, unsigned short* __restrict__ outB,
    unsigned short* __restrict__ outV, float* __restrict__ outF) {
  constexpr int BK = 64;
  constexpr int MI = BM / 32;
  const int z = blockIdx.z;
  const unsigned short* A = z == 0 ? A0 : z == 1 ? A1 : A2;
  const unsigned short* Bt = Wt + (long)z * 1048576;
  const float* bias = z == 0 ? b0 : z == 1 ? b1 : b2;
  unsigned short* outz = outB + (long)z * 4194304;
  const float bscale = (MODE == 0 && z == 0) ? QSCALE : 1.0f;

  __shared__ char lds[BM * 128 + 16384];
  char* As = lds;
  char* Bs = lds + BM * 128;
  const int tid = threadIdx.x, lane = tid & 63, w = tid >> 6;
  const int wr = w >> 1, wc = w & 1;
  const int m0 = blockIdx.x * BM, n0 = blockIdx.y * 128;
  constexpr int K = 1024;
  constexpr int ACH = BM * 8 / 256;

  f32x4 acc[MI][4] = {};
  for (int kt = 0; kt < K / BK; ++kt) {
    __syncthreads();
#pragma unroll
    for (int i = 0; i < ACH; ++i) {
      int c = tid + i * 256;
      int row = c >> 3, pg = (c & 7) ^ (row & 7);
      gload16(A + (long)(m0 + row) * K + kt * BK + pg * 8, As + c * 16);
    }
#pragma unroll
    for (int i = 0; i < 4; ++i) {
      int c = tid + i * 256;
      int row = c >> 3, pg = (c & 7) ^ (row & 7);
      gload16(Bt + (long)(n0 + row) * K + kt * BK + pg * 8, Bs + c * 16);
    }
    asm volatile("s_waitcnt vmcnt(0)" ::: "memory");
    __syncthreads();
#pragma unroll
    for (int ks = 0; ks < 2; ++ks) {
      short8 af[MI], bf[4];
#pragma unroll
      for (int mi = 0; mi < MI; ++mi) {
        int row = wr * (BM / 2) + mi * 16 + (lane & 15);
        int part = (ks * 4 + (lane >> 4)) ^ (row & 7);
        af[mi] = *(const short8*)(As + row * 128 + part * 16);
      }
#pragma unroll
      for (int ni = 0; ni < 4; ++ni) {
        int row = wc * 64 + ni * 16 + (lane & 15);
        int part = (ks * 4 + (lane >> 4)) ^ (row & 7);
        bf[ni] = *(const short8*)(Bs + row * 128 + part * 16);
      }
#pragma unroll
      for (int mi = 0; mi < MI; ++mi)
#pragma unroll
        for (int ni = 0; ni < 4; ++ni)
          acc[mi][ni] = MFMA16(af[mi], bf[ni], acc[mi][ni]);
    }
  }
#pragma unroll
  for (int mi = 0; mi < MI; ++mi) {
    int mbase = m0 + wr * (BM / 2) + mi * 16 + ((lane >> 4) << 2);
#pragma unroll
    for (int ni = 0; ni < 4; ++ni) {
      int j = n0 + wc * 64 + ni * 16 + (lane & 15);
      float bj = bias[j] * bscale;
      float t0 = acc[mi][ni][0] + bj;
      float t1 = acc[mi][ni][1] + bj;
      float t2 = acc[mi][ni][2] + bj;
      float t3 = acc[mi][ni][3] + bj;
      if constexpr (MODE == 0) {
        int b = mbase >> 11, s = mbase & 2047;
        int h = j >> 6, d = j & 63;
        if (z == 2) {
          unsigned lo, hi;
          asm("v_cvt_pk_bf16_f32 %0, %1, %2" : "=v"(lo) : "v"(t0), "v"(t1));
          asm("v_cvt_pk_bf16_f32 %0, %1, %2" : "=v"(hi) : "v"(t2), "v"(t3));
          uint2 o; o.x = lo; o.y = hi;
          // kv-slot permutation (s is 4-aligned; 4-run stays contiguous)
          int sp = (s & ~31) | (((s >> 2) & 3) << 3) | (((s >> 4) & 1) << 2);
          *(uint2*)(outV + ((long)(b * 16 + h) * 64 + d) * 2048 + sp) = o;
        } else {
          long base = (((long)(b * 16 + h)) * 2048 + s) * 64 + d;
          outz[base] = f2bf(t0);
          outz[base + 64] = f2bf(t1);
          outz[base + 128] = f2bf(t2);
          outz[base + 192] = f2bf(t3);
        }
      } else {
        outF[(long)mbase * 1024 + j] = t0;
        outF[(long)(mbase + 1) * 1024 + j] = t1;
        outF[(long)(mbase + 2) * 1024 + j] = t2;
        outF[(long)(mbase + 3) * 1024 + j] = t3;
      }
    }
  }
}

// ---------------------------------------------------------------- attention --
// R3/R9 structure (16 q/wave, 4-wave blocks, 16 waves/CU, stagger) with P held
// ENTIRELY in registers: V^T's kv columns are pre-permuted by the QKV GEMM so
// the PV A-fragment is exactly [pk(sc0.p01),pk(sc0.p23),pk(sc1.p01),pk(sc1.p23)]
// (slot 8g+j <-> kv 16*(j>=4)+4g+(j&3)). Kills 8 ds_writes + 2 ds_reads per
// wave-tile; LDS floor 312 -> 240 cyc/wave-tile.
__global__ __launch_bounds__(256, 4) void attn_kernel(
    const unsigned short* __restrict__ qh, const unsigned short* __restrict__ kh,
    const unsigned short* __restrict__ vt, const unsigned* __restrict__ mbits,
    unsigned short* __restrict__ O) {
  constexpr int S = 2048, NT = 32;
  __shared__ char lds[32768];  // K dbuf 2x8K | V dbuf 2x8K
  char* Ks = lds;
  char* Vts = lds + 16384;
  const int tid = threadIdx.x, lane = tid & 63, w = tid >> 6;
  const int g = lane >> 4, c = lane & 15;

  // XCD-bijective swizzle: 1024 blocks -> 128 consecutive (4 heads) per XCD
  const int flat = blockIdx.y * 32 + blockIdx.x;
  const int fl2 = (flat & 7) * 128 + (flat >> 3);
  const int qb = fl2 & 31, bh = fl2 >> 5, b = bh >> 4;
  const int kt0 = (fl2 & 3) * 8;  // phase stagger across co-resident blocks

  const unsigned short* qp = qh + (long)bh * S * 64;
  const unsigned short* kp = kh + (long)bh * S * 64;
  const unsigned short* vp = vt + (long)bh * 64 * S;
  unsigned short* op = O + (long)bh * S * 64;
  const unsigned* mrow = mbits + (long)b * S * 64;
  const int q0 = qb * 64 + w * 16;
  const int myq = q0 + c;

  // Q as B-frags (pre-scaled by QSCALE upstream)
  short8 bq_[2];
#pragma unroll
  for (int ds = 0; ds < 2; ++ds)
    bq_[ds] = *(const short8*)(qp + (long)myq * 64 + ds * 32 + g * 8);

  f32x4 o_acc[4] = {};
  float lpart = 0.f;

#define STAGE(KT, BUF)                                                              \
  {                                                                                 \
    _Pragma("unroll") for (int i = 0; i < 2; ++i) {                                 \
      int cc = tid + i * 256;                                                       \
      int row = cc >> 3, pg = (cc & 7) ^ (row & 7);                                 \
      gload16(kp + (long)((KT)*64 + row) * 64 + pg * 8, Ks + (BUF)*8192 + cc * 16); \
    }                                                                               \
    _Pragma("unroll") for (int i = 0; i < 2; ++i) {                                 \
      int cc = tid + i * 256;                                                       \
      int row = cc >> 3, pg = (cc & 7) ^ (row & 7);                                 \
      gload16(vp + (long)row * S + (KT)*64 + pg * 8, Vts + (BUF)*8192 + cc * 16);   \
    }                                                                               \
  }

  STAGE(kt0, 0);
  uint2 mcur = *(const uint2*)(mrow + (long)myq * 64 + kt0 * 2);
  uint2 mnxt = mcur;

  for (int kt = 0; kt < NT; ++kt) {
    const int cur = kt & 1;
    if (kt + 1 < NT) {
      const int nx = (kt0 + kt + 1) & 31;
      STAGE(nx, cur ^ 1);
      mnxt = *(const uint2*)(mrow + (long)myq * 64 + nx * 2);
      // 5 loads issued this iter (4 stage + 1 mask); drain exactly the
      // previous tile's 5 -> current K/V + mask ready, next-tile stays in flight.
      asm volatile("s_waitcnt vmcnt(5)" ::: "memory");
    } else {
      asm volatile("s_waitcnt vmcnt(0)" ::: "memory");
    }
    __builtin_amdgcn_s_barrier();

    // QK^T (swapped): sc[kf] rows = k-local, cols = q
    f32x4 sc[4] = {};
    const char* Kb = Ks + cur * 8192;
    __builtin_amdgcn_s_setprio(1);
#pragma unroll
    for (int ds = 0; ds < 2; ++ds) {
#pragma unroll
      for (int kf = 0; kf < 4; ++kf) {
        int row = kf * 16 + c;
        int part = (ds * 4 + g) ^ (row & 7);
        short8 ak = *(const short8*)(Kb + row * 128 + part * 16);
        sc[kf] = MFMA16(ak, bq_[ds], sc[kf]);
      }
    }
    __builtin_amdgcn_s_setprio(0);

    // softmax (fixed-max, pre-scaled): p = live ? 2^s : 0 -> PA regs directly
    unsigned ws0 = mcur.x >> (g * 4), ws1 = mcur.y >> (g * 4);
    unsigned pw[8];
#pragma unroll
    for (int kf = 0; kf < 4; ++kf) {
      unsigned wsh = ((kf >= 2) ? ws1 : ws0) >> ((kf & 1) * 16);
      float pv0 = __builtin_amdgcn_exp2f(sc[kf][0]);
      float pv1 = __builtin_amdgcn_exp2f(sc[kf][1]);
      float pv2 = __builtin_amdgcn_exp2f(sc[kf][2]);
      float pv3 = __builtin_amdgcn_exp2f(sc[kf][3]);
      pv0 = (wsh & 1u) ? pv0 : 0.f;
      pv1 = (wsh & 2u) ? pv1 : 0.f;
      pv2 = (wsh & 4u) ? pv2 : 0.f;
      pv3 = (wsh & 8u) ? pv3 : 0.f;
      lpart += (pv0 + pv1) + (pv2 + pv3);
      asm("v_cvt_pk_bf16_f32 %0, %1, %2" : "=v"(pw[kf * 2]) : "v"(pv0), "v"(pv1));
      asm("v_cvt_pk_bf16_f32 %0, %1, %2" : "=v"(pw[kf * 2 + 1]) : "v"(pv2), "v"(pv3));
    }
    short8 pa0 = mk8(pw[0], pw[1], pw[2], pw[3]);
    short8 pa1 = mk8(pw[4], pw[5], pw[6], pw[7]);
    mcur = mnxt;

    // PV (A = P from registers, B = permuted V^T from LDS)
    const char* Vb = Vts + cur * 8192;
    __builtin_amdgcn_s_setprio(1);
#pragma unroll
    for (int ks = 0; ks < 2; ++ks) {
      short8 pa = ks ? pa1 : pa0;
      int part = ks * 4 + g;
#pragma unroll
      for (int nd = 0; nd < 4; ++nd) {
        int d = nd * 16 + c;
        short8 bv = *(const short8*)(Vb + d * 128 + ((part ^ (d & 7)) * 16));
        o_acc[nd] = MFMA16(pa, bv, o_acc[nd]);
      }
    }
    __builtin_amdgcn_s_setprio(0);

    // drain LDS reads before barrier so next stage can't overwrite in-flight
    asm volatile("s_waitcnt lgkmcnt(0)" ::: "memory");
    __builtin_amdgcn_sched_barrier(0);
    __builtin_amdgcn_s_barrier();
  }
#undef STAGE

  // epilogue: reduce l across the 4 g-groups, divide, store
  lpart += __shfl_xor(lpart, 16);
  lpart += __shfl_xor(lpart, 32);
#pragma unroll
  for (int r = 0; r < 4; ++r) {
    float lr = __shfl(lpart, g * 4 + r);
    float inv = 1.0f / lr;
    int qrow = q0 + g * 4 + r;
#pragma unroll
    for (int nd = 0; nd < 4; ++nd)
      op[(long)qrow * 64 + nd * 16 + c] = f2bf(o_acc[nd][r] * inv);
  }
}

// ---------------------------------------------------------------- launch -----
extern "C" void kernel_launch(void* const* d_in, const int* in_sizes, int n_in,
                              void* d_out, int out_size, void* d_ws, size_t ws_size,
                              hipStream_t stream) {
  const float* q = (const float*)d_in[0];
  const float* k = (const float*)d_in[1];
  const float* v = (const float*)d_in[2];
  const int* mask = (const int*)d_in[3];
  const float* Wq = (const float*)d_in[4];
  const float* bq = (const float*)d_in[5];
  const float* Wk = (const float*)d_in[6];
  const float* bk = (const float*)d_in[7];
  const float* Wv = (const float*)d_in[8];
  const float* bv = (const float*)d_in[9];
  const float* Wo = (const float*)d_in[10];
  const float* bo = (const float*)d_in[11];
  const float* gamma = (const float*)d_in[12];
  const float* beta = (const float*)d_in[13];
  float* out = (float*)d_out;

  char* ws = (char*)d_ws;
  unsigned short* Wt = (unsigned short*)ws;                         // 8 MB
  unsigned* mbits = (unsigned*)(ws + 8u * 1024 * 1024);             // 1 MB
  unsigned short* lnq = (unsigned short*)(ws + 9u * 1024 * 1024);   // 8 MB
  unsigned short* lnk = lnq + 4194304;
  unsigned short* lnv = lnk + 4194304;
  unsigned short* qh = lnv + 4194304;
  unsigned short* kh = qh + 4194304;
  unsigned short* vtb = kh + 4194304;  // permuted V^T written by QKV GEMM (z==2)
  unsigned short* Ob = lnq;            // alias: lnq dead after QKV GEMM

  wtrans_kernel<<<dim3(16, 16, 4), 256, 0, stream>>>(Wq, Wk, Wv, Wo, Wt);
  maskpack_kernel<<<1024, 256, 0, stream>>>(mask, mbits);
  ln_kernel<<<dim3(4096, 3), 256, 0, stream>>>(q, k, v, gamma, beta, lnq, lnk, lnv);
  gemm_kernel<128, 0><<<dim3(32, 8, 3), 256, 0, stream>>>(lnq, lnk, lnv, Wt, bq, bk, bv,
                                                          qh, vtb, nullptr);
  attn_kernel<<<dim3(32, 32), 256, 0, stream>>>(qh, kh, vtb, mbits, Ob);
  gemm_kernel<64, 1><<<dim3(64, 8, 1), 256, 0, stream>>>(Ob, Ob, Ob, Wt + 3 * 1048576,
                                                         bo, bo, bo, nullptr, nullptr, out);
}

// Round 12
// 142.594 us; speedup vs baseline: 1.7115x; 1.0461x over previous
//
#include <hip/hip_runtime.h>

typedef short short8 __attribute__((ext_vector_type(8)));
typedef float f32x4 __attribute__((ext_vector_type(4)));

#define QSCALE 0.18033688011112042f  // 0.125 * log2(e), folded into Wq/bq

__device__ __forceinline__ unsigned short f2bf(float f) {
  unsigned u = __builtin_bit_cast(unsigned, f);
  u += 0x7fffu + ((u >> 16) & 1u);
  return (unsigned short)(u >> 16);
}

__device__ __forceinline__ void gload16(const void* g, void* l) {
  typedef __attribute__((address_space(1))) unsigned int gas;
  typedef __attribute__((address_space(3))) unsigned int las;
  __builtin_amdgcn_global_load_lds((gas*)(unsigned long long)g,
                                   (las*)(unsigned)(unsigned long long)l, 16, 0, 0);
}

__device__ __forceinline__ short8 mk8(unsigned r0, unsigned r1, unsigned r2, unsigned r3) {
  union { unsigned u[4]; short8 s; } t;
  t.u[0] = r0; t.u[1] = r1; t.u[2] = r2; t.u[3] = r3;
  return t.s;
}

#define MFMA16(a, b, c) __builtin_amdgcn_mfma_f32_16x16x32_bf16(a, b, c, 0, 0, 0)

// ---------------------------------------------------------------- weights ----
// W fp32 [k][n] -> Wt bf16 [n][k]; Wq additionally pre-scaled by QSCALE.
__global__ __launch_bounds__(256) void wtrans_kernel(
    const float* __restrict__ Wq, const float* __restrict__ Wk,
    const float* __restrict__ Wv, const float* __restrict__ Wo,
    unsigned short* __restrict__ Wt) {
  const int wsel = blockIdx.z;
  const float* W = wsel == 0 ? Wq : wsel == 1 ? Wk : wsel == 2 ? Wv : Wo;
  const float wscale = (wsel == 0) ? QSCALE : 1.0f;
  unsigned short* out = Wt + (long)wsel * 1048576;
  __shared__ float lds[64][65];
  const int t = threadIdx.x;
  const int k0 = blockIdx.x * 64, n0 = blockIdx.y * 64;
#pragma unroll
  for (int i = 0; i < 4; ++i) {
    int r = (t >> 4) + i * 16, c4 = (t & 15) * 4;
    float4 vv = *(const float4*)(W + (long)(k0 + r) * 1024 + n0 + c4);
    lds[r][c4] = vv.x; lds[r][c4 + 1] = vv.y; lds[r][c4 + 2] = vv.z; lds[r][c4 + 3] = vv.w;
  }
  __syncthreads();
#pragma unroll
  for (int i = 0; i < 16; ++i) {
    int flat = t + i * 256;
    int n = flat >> 6, kk = flat & 63;
    out[(long)(n0 + n) * 1024 + k0 + kk] = f2bf(lds[kk][n] * wscale);
  }
}

// ---------------------------------------------------------------- mask pack --
__global__ __launch_bounds__(256) void maskpack_kernel(const int* __restrict__ mask,
                                                       unsigned* __restrict__ bits) {
  const long n = 8388608;  // 2*2048*2048
  const long stride = (long)gridDim.x * 256;
  const int lane = threadIdx.x & 63;
  for (long i = (long)blockIdx.x * 256 + threadIdx.x; i < n; i += stride) {
    unsigned long long bal = __ballot(mask[i] != 0);
    if ((lane & 31) == 0) bits[i >> 5] = (unsigned)(bal >> (lane & 32));
  }
}

// ---------------------------------------------------------------- layernorm --
__global__ __launch_bounds__(256) void ln_kernel(
    const float* __restrict__ q, const float* __restrict__ k, const float* __restrict__ v,
    const float* __restrict__ gamma, const float* __restrict__ beta,
    unsigned short* __restrict__ lnq, unsigned short* __restrict__ lnk,
    unsigned short* __restrict__ lnv) {
  const int row = blockIdx.x, which = blockIdx.y;
  const float* x = (which == 0 ? q : which == 1 ? k : v) + (long)row * 1024;
  unsigned short* y = (which == 0 ? lnq : which == 1 ? lnk : lnv) + (long)row * 1024;
  const int t = threadIdx.x, lane = t & 63, wv = t >> 6;
  float4 xv = ((const float4*)x)[t];
  float s = xv.x + xv.y + xv.z + xv.w;
  float s2 = xv.x * xv.x + xv.y * xv.y + xv.z * xv.z + xv.w * xv.w;
#pragma unroll
  for (int off = 32; off > 0; off >>= 1) {
    s += __shfl_down(s, off);
    s2 += __shfl_down(s2, off);
  }
  __shared__ float red[8];
  if (lane == 0) { red[wv] = s; red[wv + 4] = s2; }
  __syncthreads();
  float tot = red[0] + red[1] + red[2] + red[3];
  float tot2 = red[4] + red[5] + red[6] + red[7];
  float mu = tot * (1.0f / 1024.0f);
  float var = tot2 * (1.0f / 1024.0f) - mu * mu;
  float rs = rsqrtf(var + 1e-5f);
  float4 g = ((const float4*)gamma)[t];
  float4 be = ((const float4*)beta)[t];
  ushort4 o;
  o.x = f2bf((xv.x - mu) * rs * g.x + be.x);
  o.y = f2bf((xv.y - mu) * rs * g.y + be.y);
  o.z = f2bf((xv.z - mu) * rs * g.z + be.z);
  o.w = f2bf((xv.w - mu) * rs * g.w + be.w);
  ((ushort4*)y)[t] = o;
}

// ---------------------------------------------------------------- GEMM -------
// 2-phase double-buffered K-loop (T3-minimal): BK=32, A/B tile dbuf in the same
// 32KB LDS; STAGE(kt+1) issued before ds_read(kt)+MFMA; one barrier per iter.
// 64B LDS rows use part = g ^ ((row>>1)&3) swizzle (2-way = free); gload source
// carries the inverse permutation (both-sides rule).
// MODE 0: bf16 out, heads layout [B,H,S,64]; z==2 writes V^T [BH][64][S] to outV
// with kv-slot permutation (pos = (s&~31)|((s>>2)&3)<<3|((s>>4)&1)<<2) so the
// attention's PV A-fragment is lane-local. MODE 1: fp32 out row-major.
template <int BM, int MODE>
__global__ __launch_bounds__(256) void gemm_kernel(
    const unsigned short* __restrict__ A0, const unsigned short* __restrict__ A1,
    const unsigned short* __restrict__ A2, const unsigned short* __restrict__ Wt,
    const float* __restrict__ b0, const float* __restrict__ b1,
    const float* __restrict__ b2, unsigned short* __restrict__ outB,
    unsigned short* __restrict__ outV, float* __restrict__ outF) {
  constexpr int MI = BM / 32;
  constexpr int NT = 32;           // K=1024 / BK=32
  constexpr int ACHA = BM / 64;    // A 16B-chunks per thread per stage
  const int z = blockIdx.z;
  const unsigned short* A = z == 0 ? A0 : z == 1 ? A1 : A2;
  const unsigned short* Bt = Wt + (long)z * 1048576;
  const float* bias = z == 0 ? b0 : z == 1 ? b1 : b2;
  unsigned short* outz = outB + (long)z * 4194304;
  const float bscale = (MODE == 0 && z == 0) ? QSCALE : 1.0f;

  __shared__ char lds[(BM + 128) * 128];  // A dbuf BM*64*2 | B dbuf 8192*2
  char* As = lds;
  char* Bs = lds + BM * 128;
  const int tid = threadIdx.x, lane = tid & 63, w = tid >> 6;
  const int g = lane >> 4;
  const int wr = w >> 1, wc = w & 1;
  const int m0 = blockIdx.x * BM, n0 = blockIdx.y * 128;

  f32x4 acc[MI][4] = {};

#define GSTAGE(KT, BUF)                                                       \
  {                                                                           \
    _Pragma("unroll") for (int i = 0; i < ACHA; ++i) {                        \
      int cc = tid + i * 256;                                                 \
      int row = cc >> 2, p = cc & 3;                                          \
      int kk = p ^ ((row >> 1) & 3);                                          \
      gload16(A + (long)(m0 + row) * 1024 + (KT)*32 + kk * 8,                 \
              As + (BUF) * (BM * 64) + cc * 16);                              \
    }                                                                         \
    _Pragma("unroll") for (int i = 0; i < 2; ++i) {                           \
      int cc = tid + i * 256;                                                 \
      int row = cc >> 2, p = cc & 3;                                          \
      int kk = p ^ ((row >> 1) & 3);                                          \
      gload16(Bt + (long)(n0 + row) * 1024 + (KT)*32 + kk * 8,                \
              Bs + (BUF)*8192 + cc * 16);                                     \
    }                                                                         \
  }

  GSTAGE(0, 0);
  asm volatile("s_waitcnt vmcnt(0)" ::: "memory");
  __builtin_amdgcn_s_barrier();

  for (int kt = 0; kt < NT; ++kt) {
    const int cur = kt & 1;
    if (kt + 1 < NT) GSTAGE(kt + 1, cur ^ 1);
    short8 af[MI], bf[4];
#pragma unroll
    for (int mi = 0; mi < MI; ++mi) {
      int row = wr * (BM / 2) + mi * 16 + (lane & 15);
      int part = g ^ ((row >> 1) & 3);
      af[mi] = *(const short8*)(As + cur * (BM * 64) + row * 64 + part * 16);
    }
#pragma unroll
    for (int ni = 0; ni < 4; ++ni) {
      int row = wc * 64 + ni * 16 + (lane & 15);
      int part = g ^ ((row >> 1) & 3);
      bf[ni] = *(const short8*)(Bs + cur * 8192 + row * 64 + part * 16);
    }
    __builtin_amdgcn_s_setprio(1);
#pragma unroll
    for (int mi = 0; mi < MI; ++mi)
#pragma unroll
      for (int ni = 0; ni < 4; ++ni)
        acc[mi][ni] = MFMA16(af[mi], bf[ni], acc[mi][ni]);
    __builtin_amdgcn_s_setprio(0);
    asm volatile("s_waitcnt vmcnt(0) lgkmcnt(0)" ::: "memory");
    __builtin_amdgcn_s_barrier();
  }
#undef GSTAGE

#pragma unroll
  for (int mi = 0; mi < MI; ++mi) {
    int mbase = m0 + wr * (BM / 2) + mi * 16 + ((lane >> 4) << 2);
#pragma unroll
    for (int ni = 0; ni < 4; ++ni) {
      int j = n0 + wc * 64 + ni * 16 + (lane & 15);
      float bj = bias[j] * bscale;
      float t0 = acc[mi][ni][0] + bj;
      float t1 = acc[mi][ni][1] + bj;
      float t2 = acc[mi][ni][2] + bj;
      float t3 = acc[mi][ni][3] + bj;
      if constexpr (MODE == 0) {
        int b = mbase >> 11, s = mbase & 2047;
        int h = j >> 6, d = j & 63;
        if (z == 2) {
          unsigned lo, hi;
          asm("v_cvt_pk_bf16_f32 %0, %1, %2" : "=v"(lo) : "v"(t0), "v"(t1));
          asm("v_cvt_pk_bf16_f32 %0, %1, %2" : "=v"(hi) : "v"(t2), "v"(t3));
          uint2 o; o.x = lo; o.y = hi;
          // kv-slot permutation (s is 4-aligned; 4-run stays contiguous)
          int sp = (s & ~31) | (((s >> 2) & 3) << 3) | (((s >> 4) & 1) << 2);
          *(uint2*)(outV + ((long)(b * 16 + h) * 64 + d) * 2048 + sp) = o;
        } else {
          long base = (((long)(b * 16 + h)) * 2048 + s) * 64 + d;
          outz[base] = f2bf(t0);
          outz[base + 64] = f2bf(t1);
          outz[base + 128] = f2bf(t2);
          outz[base + 192] = f2bf(t3);
        }
      } else {
        outF[(long)mbase * 1024 + j] = t0;
        outF[(long)(mbase + 1) * 1024 + j] = t1;
        outF[(long)(mbase + 2) * 1024 + j] = t2;
        outF[(long)(mbase + 3) * 1024 + j] = t3;
      }
    }
  }
}

// ---------------------------------------------------------------- attention --
// R10 (62.2 us proven): swapped-QK^T, fixed-max softmax, P fully in registers
// (V^T kv-slot-permuted upstream), K+V LDS dbuf, 16 q/wave, 4-wave blocks,
// 16 waves/CU, phase-staggered tile order.
__global__ __launch_bounds__(256, 4) void attn_kernel(
    const unsigned short* __restrict__ qh, const unsigned short* __restrict__ kh,
    const unsigned short* __restrict__ vt, const unsigned* __restrict__ mbits,
    unsigned short* __restrict__ O) {
  constexpr int S = 2048, NT = 32;
  __shared__ char lds[32768];  // K dbuf 2x8K | V dbuf 2x8K
  char* Ks = lds;
  char* Vts = lds + 16384;
  const int tid = threadIdx.x, lane = tid & 63, w = tid >> 6;
  const int g = lane >> 4, c = lane & 15;

  // XCD-bijective swizzle: 1024 blocks -> 128 consecutive (4 heads) per XCD
  const int flat = blockIdx.y * 32 + blockIdx.x;
  const int fl2 = (flat & 7) * 128 + (flat >> 3);
  const int qb = fl2 & 31, bh = fl2 >> 5, b = bh >> 4;
  const int kt0 = (fl2 & 3) * 8;  // phase stagger across co-resident blocks

  const unsigned short* qp = qh + (long)bh * S * 64;
  const unsigned short* kp = kh + (long)bh * S * 64;
  const unsigned short* vp = vt + (long)bh * 64 * S;
  unsigned short* op = O + (long)bh * S * 64;
  const unsigned* mrow = mbits + (long)b * S * 64;
  const int q0 = qb * 64 + w * 16;
  const int myq = q0 + c;

  // Q as B-frags (pre-scaled by QSCALE upstream)
  short8 bq_[2];
#pragma unroll
  for (int ds = 0; ds < 2; ++ds)
    bq_[ds] = *(const short8*)(qp + (long)myq * 64 + ds * 32 + g * 8);

  f32x4 o_acc[4] = {};
  float lpart = 0.f;

#define STAGE(KT, BUF)                                                              \
  {                                                                                 \
    _Pragma("unroll") for (int i = 0; i < 2; ++i) {                                 \
      int cc = tid + i * 256;                                                       \
      int row = cc >> 3, pg = (cc & 7) ^ (row & 7);                                 \
      gload16(kp + (long)((KT)*64 + row) * 64 + pg * 8, Ks + (BUF)*8192 + cc * 16); \
    }                                                                               \
    _Pragma("unroll") for (int i = 0; i < 2; ++i) {                                 \
      int cc = tid + i * 256;                                                       \
      int row = cc >> 3, pg = (cc & 7) ^ (row & 7);                                 \
      gload16(vp + (long)row * S + (KT)*64 + pg * 8, Vts + (BUF)*8192 + cc * 16);   \
    }                                                                               \
  }

  STAGE(kt0, 0);
  uint2 mcur = *(const uint2*)(mrow + (long)myq * 64 + kt0 * 2);
  uint2 mnxt = mcur;

  for (int kt = 0; kt < NT; ++kt) {
    const int cur = kt & 1;
    if (kt + 1 < NT) {
      const int nx = (kt0 + kt + 1) & 31;
      STAGE(nx, cur ^ 1);
      mnxt = *(const uint2*)(mrow + (long)myq * 64 + nx * 2);
      // 5 loads issued this iter (4 stage + 1 mask); drain exactly the
      // previous tile's 5 -> current K/V + mask ready, next-tile stays in flight.
      asm volatile("s_waitcnt vmcnt(5)" ::: "memory");
    } else {
      asm volatile("s_waitcnt vmcnt(0)" ::: "memory");
    }
    __builtin_amdgcn_s_barrier();

    // QK^T (swapped): sc[kf] rows = k-local, cols = q
    f32x4 sc[4] = {};
    const char* Kb = Ks + cur * 8192;
    __builtin_amdgcn_s_setprio(1);
#pragma unroll
    for (int ds = 0; ds < 2; ++ds) {
#pragma unroll
      for (int kf = 0; kf < 4; ++kf) {
        int row = kf * 16 + c;
        int part = (ds * 4 + g) ^ (row & 7);
        short8 ak = *(const short8*)(Kb + row * 128 + part * 16);
        sc[kf] = MFMA16(ak, bq_[ds], sc[kf]);
      }
    }
    __builtin_amdgcn_s_setprio(0);

    // softmax (fixed-max, pre-scaled): p = live ? 2^s : 0 -> PA regs directly
    unsigned ws0 = mcur.x >> (g * 4), ws1 = mcur.y >> (g * 4);
    unsigned pw[8];
#pragma unroll
    for (int kf = 0; kf < 4; ++kf) {
      unsigned wsh = ((kf >= 2) ? ws1 : ws0) >> ((kf & 1) * 16);
      float pv0 = __builtin_amdgcn_exp2f(sc[kf][0]);
      float pv1 = __builtin_amdgcn_exp2f(sc[kf][1]);
      float pv2 = __builtin_amdgcn_exp2f(sc[kf][2]);
      float pv3 = __builtin_amdgcn_exp2f(sc[kf][3]);
      pv0 = (wsh & 1u) ? pv0 : 0.f;
      pv1 = (wsh & 2u) ? pv1 : 0.f;
      pv2 = (wsh & 4u) ? pv2 : 0.f;
      pv3 = (wsh & 8u) ? pv3 : 0.f;
      lpart += (pv0 + pv1) + (pv2 + pv3);
      asm("v_cvt_pk_bf16_f32 %0, %1, %2" : "=v"(pw[kf * 2]) : "v"(pv0), "v"(pv1));
      asm("v_cvt_pk_bf16_f32 %0, %1, %2" : "=v"(pw[kf * 2 + 1]) : "v"(pv2), "v"(pv3));
    }
    short8 pa0 = mk8(pw[0], pw[1], pw[2], pw[3]);
    short8 pa1 = mk8(pw[4], pw[5], pw[6], pw[7]);
    mcur = mnxt;

    // PV (A = P from registers, B = permuted V^T from LDS)
    const char* Vb = Vts + cur * 8192;
    __builtin_amdgcn_s_setprio(1);
#pragma unroll
    for (int ks = 0; ks < 2; ++ks) {
      short8 pa = ks ? pa1 : pa0;
      int part = ks * 4 + g;
#pragma unroll
      for (int nd = 0; nd < 4; ++nd) {
        int d = nd * 16 + c;
        short8 bv = *(const short8*)(Vb + d * 128 + ((part ^ (d & 7)) * 16));
        o_acc[nd] = MFMA16(pa, bv, o_acc[nd]);
      }
    }
    __builtin_amdgcn_s_setprio(0);

    // drain LDS reads before barrier so next stage can't overwrite in-flight
    asm volatile("s_waitcnt lgkmcnt(0)" ::: "memory");
    __builtin_amdgcn_sched_barrier(0);
    __builtin_amdgcn_s_barrier();
  }
#undef STAGE

  // epilogue: reduce l across the 4 g-groups, divide, store
  lpart += __shfl_xor(lpart, 16);
  lpart += __shfl_xor(lpart, 32);
#pragma unroll
  for (int r = 0; r < 4; ++r) {
    float lr = __shfl(lpart, g * 4 + r);
    float inv = 1.0f / lr;
    int qrow = q0 + g * 4 + r;
#pragma unroll
    for (int nd = 0; nd < 4; ++nd)
      op[(long)qrow * 64 + nd * 16 + c] = f2bf(o_acc[nd][r] * inv);
  }
}

// ---------------------------------------------------------------- launch -----
extern "C" void kernel_launch(void* const* d_in, const int* in_sizes, int n_in,
                              void* d_out, int out_size, void* d_ws, size_t ws_size,
                              hipStream_t stream) {
  const float* q = (const float*)d_in[0];
  const float* k = (const float*)d_in[1];
  const float* v = (const float*)d_in[2];
  const int* mask = (const int*)d_in[3];
  const float* Wq = (const float*)d_in[4];
  const float* bq = (const float*)d_in[5];
  const float* Wk = (const float*)d_in[6];
  const float* bk = (const float*)d_in[7];
  const float* Wv = (const float*)d_in[8];
  const float* bv = (const float*)d_in[9];
  const float* Wo = (const float*)d_in[10];
  const float* bo = (const float*)d_in[11];
  const float* gamma = (const float*)d_in[12];
  const float* beta = (const float*)d_in[13];
  float* out = (float*)d_out;

  char* ws = (char*)d_ws;
  unsigned short* Wt = (unsigned short*)ws;                         // 8 MB
  unsigned* mbits = (unsigned*)(ws + 8u * 1024 * 1024);             // 1 MB
  unsigned short* lnq = (unsigned short*)(ws + 9u * 1024 * 1024);   // 8 MB
  unsigned short* lnk = lnq + 4194304;
  unsigned short* lnv = lnk + 4194304;
  unsigned short* qh = lnv + 4194304;
  unsigned short* kh = qh + 4194304;
  unsigned short* vtb = kh + 4194304;  // permuted V^T written by QKV GEMM (z==2)
  unsigned short* Ob = lnq;            // alias: lnq dead after QKV GEMM

  wtrans_kernel<<<dim3(16, 16, 4), 256, 0, stream>>>(Wq, Wk, Wv, Wo, Wt);
  maskpack_kernel<<<1024, 256, 0, stream>>>(mask, mbits);
  ln_kernel<<<dim3(4096, 3), 256, 0, stream>>>(q, k, v, gamma, beta, lnq, lnk, lnv);
  gemm_kernel<128, 0><<<dim3(32, 8, 3), 256, 0, stream>>>(lnq, lnk, lnv, Wt, bq, bk, bv,
                                                          qh, vtb, nullptr);
  attn_kernel<<<dim3(32, 32), 256, 0, stream>>>(qh, kh, vtb, mbits, Ob);
  gemm_kernel<64, 1><<<dim3(64, 8, 1), 256, 0, stream>>>(Ob, Ob, Ob, Wt + 3 * 1048576,
                                                         bo, bo, bo, nullptr, nullptr, out);
}

// Round 13
// 139.077 us; speedup vs baseline: 1.7547x; 1.0253x over previous
//
#include <hip/hip_runtime.h>

typedef short short8 __attribute__((ext_vector_type(8)));
typedef float f32x4 __attribute__((ext_vector_type(4)));

#define QSCALE 0.18033688011112042f  // 0.125 * log2(e), folded into Wq/bq

__device__ __forceinline__ unsigned short f2bf(float f) {
  unsigned u = __builtin_bit_cast(unsigned, f);
  u += 0x7fffu + ((u >> 16) & 1u);
  return (unsigned short)(u >> 16);
}

__device__ __forceinline__ void gload16(const void* g, void* l) {
  typedef __attribute__((address_space(1))) unsigned int gas;
  typedef __attribute__((address_space(3))) unsigned int las;
  __builtin_amdgcn_global_load_lds((gas*)(unsigned long long)g,
                                   (las*)(unsigned)(unsigned long long)l, 16, 0, 0);
}

__device__ __forceinline__ short8 mk8(unsigned r0, unsigned r1, unsigned r2, unsigned r3) {
  union { unsigned u[4]; short8 s; } t;
  t.u[0] = r0; t.u[1] = r1; t.u[2] = r2; t.u[3] = r3;
  return t.s;
}

#define MFMA16(a, b, c) __builtin_amdgcn_mfma_f32_16x16x32_bf16(a, b, c, 0, 0, 0)

// ---------------------------------------------------------------- weights ----
// W fp32 [k][n] -> Wt bf16 [n][k]; Wq additionally pre-scaled by QSCALE.
__global__ __launch_bounds__(256) void wtrans_kernel(
    const float* __restrict__ Wq, const float* __restrict__ Wk,
    const float* __restrict__ Wv, const float* __restrict__ Wo,
    unsigned short* __restrict__ Wt) {
  const int wsel = blockIdx.z;
  const float* W = wsel == 0 ? Wq : wsel == 1 ? Wk : wsel == 2 ? Wv : Wo;
  const float wscale = (wsel == 0) ? QSCALE : 1.0f;
  unsigned short* out = Wt + (long)wsel * 1048576;
  __shared__ float lds[64][65];
  const int t = threadIdx.x;
  const int k0 = blockIdx.x * 64, n0 = blockIdx.y * 64;
#pragma unroll
  for (int i = 0; i < 4; ++i) {
    int r = (t >> 4) + i * 16, c4 = (t & 15) * 4;
    float4 vv = *(const float4*)(W + (long)(k0 + r) * 1024 + n0 + c4);
    lds[r][c4] = vv.x; lds[r][c4 + 1] = vv.y; lds[r][c4 + 2] = vv.z; lds[r][c4 + 3] = vv.w;
  }
  __syncthreads();
#pragma unroll
  for (int i = 0; i < 16; ++i) {
    int flat = t + i * 256;
    int n = flat >> 6, kk = flat & 63;
    out[(long)(n0 + n) * 1024 + k0 + kk] = f2bf(lds[kk][n] * wscale);
  }
}

// ---------------------------------------------------------------- mask pack --
__global__ __launch_bounds__(256) void maskpack_kernel(const int* __restrict__ mask,
                                                       unsigned* __restrict__ bits) {
  const long n = 8388608;  // 2*2048*2048
  const long stride = (long)gridDim.x * 256;
  const int lane = threadIdx.x & 63;
  for (long i = (long)blockIdx.x * 256 + threadIdx.x; i < n; i += stride) {
    unsigned long long bal = __ballot(mask[i] != 0);
    if ((lane & 31) == 0) bits[i >> 5] = (unsigned)(bal >> (lane & 32));
  }
}

// ---------------------------------------------------------------- layernorm --
__global__ __launch_bounds__(256) void ln_kernel(
    const float* __restrict__ q, const float* __restrict__ k, const float* __restrict__ v,
    const float* __restrict__ gamma, const float* __restrict__ beta,
    unsigned short* __restrict__ lnq, unsigned short* __restrict__ lnk,
    unsigned short* __restrict__ lnv) {
  const int row = blockIdx.x, which = blockIdx.y;
  const float* x = (which == 0 ? q : which == 1 ? k : v) + (long)row * 1024;
  unsigned short* y = (which == 0 ? lnq : which == 1 ? lnk : lnv) + (long)row * 1024;
  const int t = threadIdx.x, lane = t & 63, wv = t >> 6;
  float4 xv = ((const float4*)x)[t];
  float s = xv.x + xv.y + xv.z + xv.w;
  float s2 = xv.x * xv.x + xv.y * xv.y + xv.z * xv.z + xv.w * xv.w;
#pragma unroll
  for (int off = 32; off > 0; off >>= 1) {
    s += __shfl_down(s, off);
    s2 += __shfl_down(s2, off);
  }
  __shared__ float red[8];
  if (lane == 0) { red[wv] = s; red[wv + 4] = s2; }
  __syncthreads();
  float tot = red[0] + red[1] + red[2] + red[3];
  float tot2 = red[4] + red[5] + red[6] + red[7];
  float mu = tot * (1.0f / 1024.0f);
  float var = tot2 * (1.0f / 1024.0f) - mu * mu;
  float rs = rsqrtf(var + 1e-5f);
  float4 g = ((const float4*)gamma)[t];
  float4 be = ((const float4*)beta)[t];
  ushort4 o;
  o.x = f2bf((xv.x - mu) * rs * g.x + be.x);
  o.y = f2bf((xv.y - mu) * rs * g.y + be.y);
  o.z = f2bf((xv.z - mu) * rs * g.z + be.z);
  o.w = f2bf((xv.w - mu) * rs * g.w + be.w);
  ((ushort4*)y)[t] = o;
}

// ---------------------------------------------------------------- GEMM -------
// 2-phase double-buffered K-loop (T3-minimal): BK=32, A/B tile dbuf; STAGE(kt+1)
// issued before ds_read(kt)+MFMA; one barrier per iter. 64B LDS rows swizzled
// part = g ^ ((row>>1)&3) with inverse permutation on the gload source.
// MODE 0: bf16 out, heads layout [B,H,S,64]; z==2 writes V^T [BH][64][S] to outV
// with kv-slot permutation (pos = (s&~31)|((s>>2)&3)<<3|((s>>4)&1)<<2) so the
// attention's PV A-fragment is lane-local. MODE 1: fp32 out row-major.
template <int BM, int MODE>
__global__ __launch_bounds__(256) void gemm_kernel(
    const unsigned short* __restrict__ A0, const unsigned short* __restrict__ A1,
    const unsigned short* __restrict__ A2, const unsigned short* __restrict__ Wt,
    const float* __restrict__ b0, const float* __restrict__ b1,
    const float* __restrict__ b2, unsigned short* __restrict__ outB,
    unsigned short* __restrict__ outV, float* __restrict__ outF) {
  constexpr int MI = BM / 32;
  constexpr int NT = 32;           // K=1024 / BK=32
  constexpr int ACHA = BM / 64;    // A 16B-chunks per thread per stage
  const int z = blockIdx.z;
  const unsigned short* A = z == 0 ? A0 : z == 1 ? A1 : A2;
  const unsigned short* Bt = Wt + (long)z * 1048576;
  const float* bias = z == 0 ? b0 : z == 1 ? b1 : b2;
  unsigned short* outz = outB + (long)z * 4194304;
  const float bscale = (MODE == 0 && z == 0) ? QSCALE : 1.0f;

  __shared__ char lds[(BM + 128) * 128];  // A dbuf BM*64*2 | B dbuf 8192*2
  char* As = lds;
  char* Bs = lds + BM * 128;
  const int tid = threadIdx.x, lane = tid & 63, w = tid >> 6;
  const int g = lane >> 4;
  const int wr = w >> 1, wc = w & 1;
  const int m0 = blockIdx.x * BM, n0 = blockIdx.y * 128;

  f32x4 acc[MI][4] = {};

#define GSTAGE(KT, BUF)                                                       \
  {                                                                           \
    _Pragma("unroll") for (int i = 0; i < ACHA; ++i) {                        \
      int cc = tid + i * 256;                                                 \
      int row = cc >> 2, p = cc & 3;                                          \
      int kk = p ^ ((row >> 1) & 3);                                          \
      gload16(A + (long)(m0 + row) * 1024 + (KT)*32 + kk * 8,                 \
              As + (BUF) * (BM * 64) + cc * 16);                              \
    }                                                                         \
    _Pragma("unroll") for (int i = 0; i < 2; ++i) {                           \
      int cc = tid + i * 256;                                                 \
      int row = cc >> 2, p = cc & 3;                                          \
      int kk = p ^ ((row >> 1) & 3);                                          \
      gload16(Bt + (long)(n0 + row) * 1024 + (KT)*32 + kk * 8,                \
              Bs + (BUF)*8192 + cc * 16);                                     \
    }                                                                         \
  }

  GSTAGE(0, 0);
  asm volatile("s_waitcnt vmcnt(0)" ::: "memory");
  __builtin_amdgcn_s_barrier();

  for (int kt = 0; kt < NT; ++kt) {
    const int cur = kt & 1;
    if (kt + 1 < NT) GSTAGE(kt + 1, cur ^ 1);
    short8 af[MI], bf[4];
#pragma unroll
    for (int mi = 0; mi < MI; ++mi) {
      int row = wr * (BM / 2) + mi * 16 + (lane & 15);
      int part = g ^ ((row >> 1) & 3);
      af[mi] = *(const short8*)(As + cur * (BM * 64) + row * 64 + part * 16);
    }
#pragma unroll
    for (int ni = 0; ni < 4; ++ni) {
      int row = wc * 64 + ni * 16 + (lane & 15);
      int part = g ^ ((row >> 1) & 3);
      bf[ni] = *(const short8*)(Bs + cur * 8192 + row * 64 + part * 16);
    }
    __builtin_amdgcn_s_setprio(1);
#pragma unroll
    for (int mi = 0; mi < MI; ++mi)
#pragma unroll
      for (int ni = 0; ni < 4; ++ni)
        acc[mi][ni] = MFMA16(af[mi], bf[ni], acc[mi][ni]);
    __builtin_amdgcn_s_setprio(0);
    asm volatile("s_waitcnt vmcnt(0) lgkmcnt(0)" ::: "memory");
    __builtin_amdgcn_s_barrier();
  }
#undef GSTAGE

#pragma unroll
  for (int mi = 0; mi < MI; ++mi) {
    int mbase = m0 + wr * (BM / 2) + mi * 16 + ((lane >> 4) << 2);
#pragma unroll
    for (int ni = 0; ni < 4; ++ni) {
      int j = n0 + wc * 64 + ni * 16 + (lane & 15);
      float bj = bias[j] * bscale;
      float t0 = acc[mi][ni][0] + bj;
      float t1 = acc[mi][ni][1] + bj;
      float t2 = acc[mi][ni][2] + bj;
      float t3 = acc[mi][ni][3] + bj;
      if constexpr (MODE == 0) {
        int b = mbase >> 11, s = mbase & 2047;
        int h = j >> 6, d = j & 63;
        if (z == 2) {
          unsigned lo, hi;
          asm("v_cvt_pk_bf16_f32 %0, %1, %2" : "=v"(lo) : "v"(t0), "v"(t1));
          asm("v_cvt_pk_bf16_f32 %0, %1, %2" : "=v"(hi) : "v"(t2), "v"(t3));
          uint2 o; o.x = lo; o.y = hi;
          // kv-slot permutation (s is 4-aligned; 4-run stays contiguous)
          int sp = (s & ~31) | (((s >> 2) & 3) << 3) | (((s >> 4) & 1) << 2);
          *(uint2*)(outV + ((long)(b * 16 + h) * 64 + d) * 2048 + sp) = o;
        } else {
          long base = (((long)(b * 16 + h)) * 2048 + s) * 64 + d;
          outz[base] = f2bf(t0);
          outz[base + 64] = f2bf(t1);
          outz[base + 128] = f2bf(t2);
          outz[base + 192] = f2bf(t3);
        }
      } else {
        outF[(long)mbase * 1024 + j] = t0;
        outF[(long)(mbase + 1) * 1024 + j] = t1;
        outF[(long)(mbase + 2) * 1024 + j] = t2;
        outF[(long)(mbase + 3) * 1024 + j] = t3;
      }
    }
  }
}

// ---------------------------------------------------------------- attention --
// R10 base (swapped-QK^T, fixed-max softmax, P fully in registers, permuted
// V^T, K+V LDS dbuf, stagger) with 32 q-rows per wave (2 q-groups): each K/V
// LDS fragment read once feeds BOTH q-groups' MFMAs -> LDS traffic per CU
// halves. Blocks: 4 waves = 128 q; grid 512 (2 blocks/CU, 8 waves/CU).
__global__ __launch_bounds__(256, 2) void attn_kernel(
    const unsigned short* __restrict__ qh, const unsigned short* __restrict__ kh,
    const unsigned short* __restrict__ vt, const unsigned* __restrict__ mbits,
    unsigned short* __restrict__ O) {
  constexpr int S = 2048, NT = 32;
  __shared__ char lds[32768];  // K dbuf 2x8K | V dbuf 2x8K
  char* Ks = lds;
  char* Vts = lds + 16384;
  const int tid = threadIdx.x, lane = tid & 63, w = tid >> 6;
  const int g = lane >> 4, c = lane & 15;

  // XCD-bijective swizzle: 512 blocks -> 64 consecutive per XCD
  const int flat = blockIdx.y * 16 + blockIdx.x;
  const int fl2 = (flat & 7) * 64 + (flat >> 3);
  const int qb = fl2 & 15, bh = fl2 >> 4, b = bh >> 4;
  const int kt0 = (fl2 & 3) * 8;  // phase stagger across co-resident blocks

  const unsigned short* qp = qh + (long)bh * S * 64;
  const unsigned short* kp = kh + (long)bh * S * 64;
  const unsigned short* vp = vt + (long)bh * 64 * S;
  unsigned short* op = O + (long)bh * S * 64;
  const unsigned* mrow = mbits + (long)b * S * 64;
  const int q0 = qb * 128 + w * 32;
  const int myq0 = q0 + c, myq1 = q0 + 16 + c;

  // Q as B-frags (pre-scaled by QSCALE upstream), 2 q-groups
  short8 bq_[2][2];
#pragma unroll
  for (int qg = 0; qg < 2; ++qg)
#pragma unroll
    for (int ds = 0; ds < 2; ++ds)
      bq_[qg][ds] = *(const short8*)(qp + (long)(q0 + qg * 16 + c) * 64 + ds * 32 + g * 8);

  f32x4 o_acc[2][4] = {};
  float lp0 = 0.f, lp1 = 0.f;

#define STAGE(KT, BUF)                                                              \
  {                                                                                 \
    _Pragma("unroll") for (int i = 0; i < 2; ++i) {                                 \
      int cc = tid + i * 256;                                                       \
      int row = cc >> 3, pg = (cc & 7) ^ (row & 7);                                 \
      gload16(kp + (long)((KT)*64 + row) * 64 + pg * 8, Ks + (BUF)*8192 + cc * 16); \
    }                                                                               \
    _Pragma("unroll") for (int i = 0; i < 2; ++i) {                                 \
      int cc = tid + i * 256;                                                       \
      int row = cc >> 3, pg = (cc & 7) ^ (row & 7);                                 \
      gload16(vp + (long)row * S + (KT)*64 + pg * 8, Vts + (BUF)*8192 + cc * 16);   \
    }                                                                               \
  }

  // softmax (fixed-max, pre-scaled) for one q-group -> PA registers
#define SOFTMAX(SC, MC, LP, PA0, PA1)                                               \
  {                                                                                 \
    unsigned ws0 = MC.x >> (g * 4), ws1 = MC.y >> (g * 4);                          \
    unsigned pw[8];                                                                 \
    _Pragma("unroll") for (int kf = 0; kf < 4; ++kf) {                              \
      unsigned wsh = ((kf >= 2) ? ws1 : ws0) >> ((kf & 1) * 16);                    \
      float pv0 = __builtin_amdgcn_exp2f(SC[kf][0]);                                \
      float pv1 = __builtin_amdgcn_exp2f(SC[kf][1]);                                \
      float pv2 = __builtin_amdgcn_exp2f(SC[kf][2]);                                \
      float pv3 = __builtin_amdgcn_exp2f(SC[kf][3]);                                \
      pv0 = (wsh & 1u) ? pv0 : 0.f;                                                 \
      pv1 = (wsh & 2u) ? pv1 : 0.f;                                                 \
      pv2 = (wsh & 4u) ? pv2 : 0.f;                                                 \
      pv3 = (wsh & 8u) ? pv3 : 0.f;                                                 \
      LP += (pv0 + pv1) + (pv2 + pv3);                                              \
      asm("v_cvt_pk_bf16_f32 %0, %1, %2" : "=v"(pw[kf * 2]) : "v"(pv0), "v"(pv1));  \
      asm("v_cvt_pk_bf16_f32 %0, %1, %2" : "=v"(pw[kf * 2 + 1]) : "v"(pv2), "v"(pv3)); \
    }                                                                               \
    PA0 = mk8(pw[0], pw[1], pw[2], pw[3]);                                          \
    PA1 = mk8(pw[4], pw[5], pw[6], pw[7]);                                          \
  }

  STAGE(kt0, 0);
  uint2 m0c = *(const uint2*)(mrow + (long)myq0 * 64 + kt0 * 2);
  uint2 m1c = *(const uint2*)(mrow + (long)myq1 * 64 + kt0 * 2);
  uint2 m0n, m1n;

  for (int kt = 0; kt < NT; ++kt) {
    const int cur = kt & 1;
    if (kt + 1 < NT) {
      const int nx = (kt0 + kt + 1) & 31;
      STAGE(nx, cur ^ 1);
      m0n = *(const uint2*)(mrow + (long)myq0 * 64 + nx * 2);
      m1n = *(const uint2*)(mrow + (long)myq1 * 64 + nx * 2);
      // 6 loads issued this iter (4 stage + 2 masks); drain the previous 6.
      asm volatile("s_waitcnt vmcnt(6)" ::: "memory");
    } else {
      asm volatile("s_waitcnt vmcnt(0)" ::: "memory");
    }
    __builtin_amdgcn_s_barrier();

    // QK^T (swapped): each K-frag read feeds both q-groups
    f32x4 sc0[4] = {}, sc1[4] = {};
    const char* Kb = Ks + cur * 8192;
    __builtin_amdgcn_s_setprio(1);
#pragma unroll
    for (int ds = 0; ds < 2; ++ds) {
#pragma unroll
      for (int kf = 0; kf < 4; ++kf) {
        int row = kf * 16 + c;
        int part = (ds * 4 + g) ^ (row & 7);
        short8 ak = *(const short8*)(Kb + row * 128 + part * 16);
        sc0[kf] = MFMA16(ak, bq_[0][ds], sc0[kf]);
        sc1[kf] = MFMA16(ak, bq_[1][ds], sc1[kf]);
      }
    }
    __builtin_amdgcn_s_setprio(0);

    short8 pa00, pa01, pa10, pa11;
    SOFTMAX(sc0, m0c, lp0, pa00, pa01);
    SOFTMAX(sc1, m1c, lp1, pa10, pa11);
    m0c = m0n;
    m1c = m1n;

    // PV: each V-frag read feeds both q-groups
    const char* Vb = Vts + cur * 8192;
    __builtin_amdgcn_s_setprio(1);
#pragma unroll
    for (int ks = 0; ks < 2; ++ks) {
      short8 paA = ks ? pa01 : pa00;
      short8 paB = ks ? pa11 : pa10;
      int part = ks * 4 + g;
#pragma unroll
      for (int nd = 0; nd < 4; ++nd) {
        int d = nd * 16 + c;
        short8 bv = *(const short8*)(Vb + d * 128 + ((part ^ (d & 7)) * 16));
        o_acc[0][nd] = MFMA16(paA, bv, o_acc[0][nd]);
        o_acc[1][nd] = MFMA16(paB, bv, o_acc[1][nd]);
      }
    }
    __builtin_amdgcn_s_setprio(0);

    // drain LDS reads before barrier so next stage can't overwrite in-flight
    asm volatile("s_waitcnt lgkmcnt(0)" ::: "memory");
    __builtin_amdgcn_sched_barrier(0);
    __builtin_amdgcn_s_barrier();
  }
#undef SOFTMAX
#undef STAGE

  // epilogue: reduce l across the 4 g-groups, divide, store (both q-groups)
  lp0 += __shfl_xor(lp0, 16);
  lp0 += __shfl_xor(lp0, 32);
  lp1 += __shfl_xor(lp1, 16);
  lp1 += __shfl_xor(lp1, 32);
#pragma unroll
  for (int r = 0; r < 4; ++r) {
    float lr0 = __shfl(lp0, g * 4 + r);
    float lr1 = __shfl(lp1, g * 4 + r);
    float inv0 = 1.0f / lr0;
    float inv1 = 1.0f / lr1;
    int qrow0 = q0 + g * 4 + r;
    int qrow1 = q0 + 16 + g * 4 + r;
#pragma unroll
    for (int nd = 0; nd < 4; ++nd) {
      op[(long)qrow0 * 64 + nd * 16 + c] = f2bf(o_acc[0][nd][r] * inv0);
      op[(long)qrow1 * 64 + nd * 16 + c] = f2bf(o_acc[1][nd][r] * inv1);
    }
  }
}

// ---------------------------------------------------------------- launch -----
extern "C" void kernel_launch(void* const* d_in, const int* in_sizes, int n_in,
                              void* d_out, int out_size, void* d_ws, size_t ws_size,
                              hipStream_t stream) {
  const float* q = (const float*)d_in[0];
  const float* k = (const float*)d_in[1];
  const float* v = (const float*)d_in[2];
  const int* mask = (const int*)d_in[3];
  const float* Wq = (const float*)d_in[4];
  const float* bq = (const float*)d_in[5];
  const float* Wk = (const float*)d_in[6];
  const float* bk = (const float*)d_in[7];
  const float* Wv = (const float*)d_in[8];
  const float* bv = (const float*)d_in[9];
  const float* Wo = (const float*)d_in[10];
  const float* bo = (const float*)d_in[11];
  const float* gamma = (const float*)d_in[12];
  const float* beta = (const float*)d_in[13];
  float* out = (float*)d_out;

  char* ws = (char*)d_ws;
  unsigned short* Wt = (unsigned short*)ws;                         // 8 MB
  unsigned* mbits = (unsigned*)(ws + 8u * 1024 * 1024);             // 1 MB
  unsigned short* lnq = (unsigned short*)(ws + 9u * 1024 * 1024);   // 8 MB
  unsigned short* lnk = lnq + 4194304;
  unsigned short* lnv = lnk + 4194304;
  unsigned short* qh = lnv + 4194304;
  unsigned short* kh = qh + 4194304;
  unsigned short* vtb = kh + 4194304;  // permuted V^T written by QKV GEMM (z==2)
  unsigned short* Ob = lnq;            // alias: lnq dead after QKV GEMM

  wtrans_kernel<<<dim3(16, 16, 4), 256, 0, stream>>>(Wq, Wk, Wv, Wo, Wt);
  maskpack_kernel<<<1024, 256, 0, stream>>>(mask, mbits);
  ln_kernel<<<dim3(4096, 3), 256, 0, stream>>>(q, k, v, gamma, beta, lnq, lnk, lnv);
  gemm_kernel<128, 0><<<dim3(32, 8, 3), 256, 0, stream>>>(lnq, lnk, lnv, Wt, bq, bk, bv,
                                                          qh, vtb, nullptr);
  attn_kernel<<<dim3(16, 32), 256, 0, stream>>>(qh, kh, vtb, mbits, Ob);
  gemm_kernel<64, 1><<<dim3(64, 8, 1), 256, 0, stream>>>(Ob, Ob, Ob, Wt + 3 * 1048576,
                                                         bo, bo, bo, nullptr, nullptr, out);
}